// Round 1
// baseline (2405.608 us; speedup 1.0000x reference)
//
#include <hip/hip_runtime.h>
#include <math.h>

constexpr int BSZ = 2, SEQ = 2048, DM = 1024, DFF = 4096, NH = 16, DH = 64;
constexpr int MROWS = BSZ * SEQ;  // 4096

// ---------------------------------------------------------------------------
// GEMM: C[M,N] = A[M,K] * B[N,K]^T (+bias) (+relu)     (nn.Linear: y = x W^T)
// 128x128 tile, BK=16, 256 threads, 8x8 per thread, LDS transposed + padded.
// ---------------------------------------------------------------------------
template <bool BIAS, bool RELU>
__global__ __launch_bounds__(256) void gemm_nt(const float* __restrict__ A,
                                               const float* __restrict__ Bw,
                                               const float* __restrict__ bias,
                                               float* __restrict__ C,
                                               int M, int N, int K) {
  constexpr int BM = 128, BN = 128, BK = 16, PAD = 4;
  __shared__ float Al[BK][BM + PAD];
  __shared__ float Bl[BK][BN + PAD];

  const int tid = threadIdx.x;
  const int tx = tid & 15;        // 0..15 -> col group
  const int ty = tid >> 4;        // 0..15 -> row group
  const int bx = blockIdx.x, by = blockIdx.y;
  const int row0 = by * BM, col0 = bx * BN;

  // staging: each thread loads 8 floats of A tile and 8 of B tile
  const int lr = tid >> 1;          // 0..127 (tile row)
  const int lk = (tid & 1) * 8;     // 0 or 8 (k offset)

  float acc[8][8];
#pragma unroll
  for (int i = 0; i < 8; ++i)
#pragma unroll
    for (int j = 0; j < 8; ++j) acc[i][j] = 0.f;

  const float* aptr = A + (size_t)(row0 + lr) * K + lk;
  const float* bptr = Bw + (size_t)(col0 + lr) * K + lk;

  for (int k0 = 0; k0 < K; k0 += BK) {
    float4 a0 = *(const float4*)(aptr + k0);
    float4 a1 = *(const float4*)(aptr + k0 + 4);
    float4 b0 = *(const float4*)(bptr + k0);
    float4 b1 = *(const float4*)(bptr + k0 + 4);
    __syncthreads();  // previous iter's reads done before overwrite
    Al[lk + 0][lr] = a0.x; Al[lk + 1][lr] = a0.y;
    Al[lk + 2][lr] = a0.z; Al[lk + 3][lr] = a0.w;
    Al[lk + 4][lr] = a1.x; Al[lk + 5][lr] = a1.y;
    Al[lk + 6][lr] = a1.z; Al[lk + 7][lr] = a1.w;
    Bl[lk + 0][lr] = b0.x; Bl[lk + 1][lr] = b0.y;
    Bl[lk + 2][lr] = b0.z; Bl[lk + 3][lr] = b0.w;
    Bl[lk + 4][lr] = b1.x; Bl[lk + 5][lr] = b1.y;
    Bl[lk + 6][lr] = b1.z; Bl[lk + 7][lr] = b1.w;
    __syncthreads();

#pragma unroll
    for (int k = 0; k < BK; ++k) {
      float4 av0 = *(const float4*)&Al[k][ty * 8];
      float4 av1 = *(const float4*)&Al[k][ty * 8 + 4];
      float4 bv0 = *(const float4*)&Bl[k][tx * 8];
      float4 bv1 = *(const float4*)&Bl[k][tx * 8 + 4];
      float a[8] = {av0.x, av0.y, av0.z, av0.w, av1.x, av1.y, av1.z, av1.w};
      float b[8] = {bv0.x, bv0.y, bv0.z, bv0.w, bv1.x, bv1.y, bv1.z, bv1.w};
#pragma unroll
      for (int i = 0; i < 8; ++i)
#pragma unroll
        for (int j = 0; j < 8; ++j) acc[i][j] = fmaf(a[i], b[j], acc[i][j]);
    }
  }

  float bv[8];
#pragma unroll
  for (int j = 0; j < 8; ++j)
    bv[j] = BIAS ? bias[col0 + tx * 8 + j] : 0.f;

#pragma unroll
  for (int i = 0; i < 8; ++i) {
    const int row = row0 + ty * 8 + i;
    float* cp = C + (size_t)row * N + col0 + tx * 8;
#pragma unroll
    for (int j4 = 0; j4 < 2; ++j4) {
      float4 v;
      v.x = acc[i][j4 * 4 + 0] + bv[j4 * 4 + 0];
      v.y = acc[i][j4 * 4 + 1] + bv[j4 * 4 + 1];
      v.z = acc[i][j4 * 4 + 2] + bv[j4 * 4 + 2];
      v.w = acc[i][j4 * 4 + 3] + bv[j4 * 4 + 3];
      if (RELU) {
        v.x = fmaxf(v.x, 0.f); v.y = fmaxf(v.y, 0.f);
        v.z = fmaxf(v.z, 0.f); v.w = fmaxf(v.w, 0.f);
      }
      *(float4*)(cp + j4 * 4) = v;
    }
  }
}

// ---------------------------------------------------------------------------
// Flash-style attention, fp32. One thread per q-row; K/V tiles in LDS read
// via same-address broadcast (conflict-free). Online softmax.
// Q/K/V layout: [B, S, NH*DH] with head h at cols h*DH.
// ---------------------------------------------------------------------------
__global__ __launch_bounds__(256) void attention(
    const float* __restrict__ Q, const float* __restrict__ Kb,
    const float* __restrict__ V, const int* __restrict__ mask,
    float* __restrict__ O) {
  constexpr int KB = 32;
  __shared__ float Kl[KB][DH];
  __shared__ float Vl[KB][DH];
  __shared__ int ml[KB];

  const int tid = threadIdx.x;
  const int qrow = blockIdx.x * 256 + tid;  // 0..SEQ-1
  const int bh = blockIdx.y;                // 0..BSZ*NH-1
  const int b = bh >> 4, h = bh & 15;

  const float* qptr = Q + ((size_t)(b * SEQ + qrow)) * DM + h * DH;
  float4 q[16];
#pragma unroll
  for (int i = 0; i < 16; ++i) q[i] = *(const float4*)(qptr + 4 * i);

  float4 acc[16];
#pragma unroll
  for (int i = 0; i < 16; ++i) acc[i] = make_float4(0.f, 0.f, 0.f, 0.f);
  float m = -1e30f, l = 0.f;

  const int sr = tid >> 3;        // 0..31 staging row
  const int sc = (tid & 7) * 8;   // staging col

  for (int kt = 0; kt < SEQ; kt += KB) {
    const float* kp = Kb + ((size_t)(b * SEQ + kt + sr)) * DM + h * DH + sc;
    const float* vp = V + ((size_t)(b * SEQ + kt + sr)) * DM + h * DH + sc;
    float4 k0 = *(const float4*)kp, k1 = *(const float4*)(kp + 4);
    float4 v0 = *(const float4*)vp, v1 = *(const float4*)(vp + 4);
    __syncthreads();
    *(float4*)&Kl[sr][sc] = k0; *(float4*)&Kl[sr][sc + 4] = k1;
    *(float4*)&Vl[sr][sc] = v0; *(float4*)&Vl[sr][sc + 4] = v1;
    if (tid < KB) ml[tid] = mask[b * SEQ + kt + tid];
    __syncthreads();

    float s[KB];
#pragma unroll
    for (int kk = 0; kk < KB; ++kk) {
      const float4* kr = (const float4*)Kl[kk];
      float sacc = 0.f;
#pragma unroll
      for (int i = 0; i < 16; ++i) {
        float4 kv = kr[i];
        sacc = fmaf(q[i].x, kv.x, sacc);
        sacc = fmaf(q[i].y, kv.y, sacc);
        sacc = fmaf(q[i].z, kv.z, sacc);
        sacc = fmaf(q[i].w, kv.w, sacc);
      }
      s[kk] = (ml[kk] == 0) ? -3e38f : sacc * 0.125f;
    }

    float tm = s[0];
#pragma unroll
    for (int kk = 1; kk < KB; ++kk) tm = fmaxf(tm, s[kk]);
    const float mn = fmaxf(m, tm);
    const float scale = __expf(m - mn);
    l *= scale;
#pragma unroll
    for (int i = 0; i < 16; ++i) {
      acc[i].x *= scale; acc[i].y *= scale;
      acc[i].z *= scale; acc[i].w *= scale;
    }
#pragma unroll
    for (int kk = 0; kk < KB; ++kk) {
      const float p = __expf(s[kk] - mn);
      l += p;
      const float4* vr = (const float4*)Vl[kk];
#pragma unroll
      for (int i = 0; i < 16; ++i) {
        float4 vv = vr[i];
        acc[i].x = fmaf(p, vv.x, acc[i].x);
        acc[i].y = fmaf(p, vv.y, acc[i].y);
        acc[i].z = fmaf(p, vv.z, acc[i].z);
        acc[i].w = fmaf(p, vv.w, acc[i].w);
      }
    }
    m = mn;
  }

  const float inv = 1.f / l;
  float* op = O + ((size_t)(b * SEQ + qrow)) * DM + h * DH;
#pragma unroll
  for (int i = 0; i < 16; ++i) {
    float4 r;
    r.x = acc[i].x * inv; r.y = acc[i].y * inv;
    r.z = acc[i].z * inv; r.w = acc[i].w * inv;
    *(float4*)(op + 4 * i) = r;
  }
}

// ---------------------------------------------------------------------------
// Fused residual-add + LayerNorm (torch style: /(std_biased + eps)).
// One block per row (1024 cols), 256 threads x float4.
// ---------------------------------------------------------------------------
__global__ __launch_bounds__(256) void ln_add(const float* __restrict__ A,
                                              const float* __restrict__ Bx,
                                              const float* __restrict__ g,
                                              const float* __restrict__ be,
                                              float* __restrict__ out) {
  __shared__ float red[2][4];
  __shared__ float mu_s, sig_s;
  const int row = blockIdx.x;
  const int tid = threadIdx.x;

  const float4 a = *(const float4*)(A + (size_t)row * DM + tid * 4);
  const float4 b = *(const float4*)(Bx + (size_t)row * DM + tid * 4);
  float4 s = make_float4(a.x + b.x, a.y + b.y, a.z + b.z, a.w + b.w);

  float sum = s.x + s.y + s.z + s.w;
  float sq = s.x * s.x + s.y * s.y + s.z * s.z + s.w * s.w;
#pragma unroll
  for (int off = 32; off >= 1; off >>= 1) {
    sum += __shfl_xor(sum, off);
    sq += __shfl_xor(sq, off);
  }
  const int wid = tid >> 6;
  if ((tid & 63) == 0) { red[0][wid] = sum; red[1][wid] = sq; }
  __syncthreads();
  if (tid == 0) {
    float ts = red[0][0] + red[0][1] + red[0][2] + red[0][3];
    float tq = red[1][0] + red[1][1] + red[1][2] + red[1][3];
    float mu = ts * (1.f / DM);
    float var = tq * (1.f / DM) - mu * mu;
    mu_s = mu;
    sig_s = sqrtf(fmaxf(var, 0.f)) + 1e-6f;
  }
  __syncthreads();
  const float mu = mu_s, inv = 1.f / sig_s;
  const float4 gv = *(const float4*)(g + tid * 4);
  const float4 bv = *(const float4*)(be + tid * 4);
  float4 o;
  o.x = (s.x - mu) * inv * gv.x + bv.x;
  o.y = (s.y - mu) * inv * gv.y + bv.y;
  o.z = (s.z - mu) * inv * gv.z + bv.z;
  o.w = (s.w - mu) * inv * gv.w + bv.w;
  *(float4*)(out + (size_t)row * DM + tid * 4) = o;
}

// ---------------------------------------------------------------------------
extern "C" void kernel_launch(void* const* d_in, const int* in_sizes, int n_in,
                              void* d_out, int out_size, void* d_ws,
                              size_t ws_size, hipStream_t stream) {
  const float* x  = (const float*)d_in[0];
  const int* mask = (const int*)d_in[1];
  const float* Wq = (const float*)d_in[2];
  const float* Wk = (const float*)d_in[3];
  const float* Wv = (const float*)d_in[4];
  const float* Wo = (const float*)d_in[5];
  const float* w1 = (const float*)d_in[6];
  const float* b1 = (const float*)d_in[7];
  const float* w2 = (const float*)d_in[8];
  const float* b2 = (const float*)d_in[9];
  const float* g1 = (const float*)d_in[10];
  const float* be1 = (const float*)d_in[11];
  const float* g2 = (const float*)d_in[12];
  const float* be2 = (const float*)d_in[13];
  float* out = (float*)d_out;

  float* ws = (float*)d_ws;
  constexpr size_t SZ = (size_t)MROWS * DM;  // 4.19M floats
  float* bufA = ws + 0 * SZ;  // Q, then X1
  float* bufB = ws + 1 * SZ;  // K, then X3
  float* bufC = ws + 2 * SZ;  // V, then X2
  float* bufD = ws + 3 * SZ;  // O, then (head of) FFN hidden H
  float* bufH = bufD;         // H spans 4*SZ starting here (O dead by then)

  const dim3 blk(256);
  const dim3 gP(DM / 128, MROWS / 128);    // N=1024 GEMMs
  const dim3 gF(DFF / 128, MROWS / 128);   // N=4096 GEMM

  gemm_nt<false, false><<<gP, blk, 0, stream>>>(x, Wq, nullptr, bufA, MROWS, DM, DM);
  gemm_nt<false, false><<<gP, blk, 0, stream>>>(x, Wk, nullptr, bufB, MROWS, DM, DM);
  gemm_nt<false, false><<<gP, blk, 0, stream>>>(x, Wv, nullptr, bufC, MROWS, DM, DM);

  attention<<<dim3(SEQ / 256, BSZ * NH), blk, 0, stream>>>(bufA, bufB, bufC, mask, bufD);

  gemm_nt<false, false><<<gP, blk, 0, stream>>>(bufD, Wo, nullptr, bufA, MROWS, DM, DM);
  ln_add<<<dim3(MROWS), blk, 0, stream>>>(bufA, x, g1, be1, bufC);

  gemm_nt<true, true><<<gF, blk, 0, stream>>>(bufC, w1, b1, bufH, MROWS, DFF, DM);
  gemm_nt<true, false><<<gP, blk, 0, stream>>>(bufH, w2, b2, bufB, MROWS, DM, DFF);

  ln_add<<<dim3(MROWS), blk, 0, stream>>>(bufC, bufB, g2, be2, out);
}

// Round 3
// 1577.857 us; speedup vs baseline: 1.5246x; 1.5246x over previous
//
#include <hip/hip_runtime.h>
#include <math.h>

typedef __attribute__((ext_vector_type(8))) short bf16x8;
typedef __attribute__((ext_vector_type(4))) float f32x4;
typedef __attribute__((ext_vector_type(8))) unsigned short us8;
typedef unsigned short u16;

constexpr int BSZ = 2, SEQ = 2048, DM = 1024, DFF = 4096, NH = 16, DH = 64;
constexpr int MROWS = BSZ * SEQ;  // 4096

__device__ __forceinline__ float bf2f(u16 u) {
  union { unsigned int i; float f; } v; v.i = ((unsigned int)u) << 16; return v.f;
}
__device__ __forceinline__ u16 f2bf(float f) {
  union { float f; unsigned int i; } v; v.f = f;
  unsigned int r = v.i + 0x7fffu + ((v.i >> 16) & 1u);
  return (u16)(r >> 16);
}

#define GLOAD16(gp, lp) __builtin_amdgcn_global_load_lds( \
    (const __attribute__((address_space(1))) void*)(gp),  \
    (__attribute__((address_space(3))) void*)(lp), 16, 0, 0)

// ---------------------------------------------------------------------------
// fp32 -> bf16 convert (RNE), 8 elements/thread
// ---------------------------------------------------------------------------
__global__ __launch_bounds__(256) void cvt_bf16(const float* __restrict__ in,
                                                u16* __restrict__ out, int n) {
  const int i = (blockIdx.x * 256 + threadIdx.x) * 8;
  if (i >= n) return;
  const float4 a = *(const float4*)(in + i);
  const float4 b = *(const float4*)(in + i + 4);
  uint4 o;
  o.x = f2bf(a.x) | ((unsigned)f2bf(a.y) << 16);
  o.y = f2bf(a.z) | ((unsigned)f2bf(a.w) << 16);
  o.z = f2bf(b.x) | ((unsigned)f2bf(b.y) << 16);
  o.w = f2bf(b.z) | ((unsigned)f2bf(b.w) << 16);
  *(uint4*)(out + i) = o;
}

// ---------------------------------------------------------------------------
// bf16 MFMA GEMM (m97 structure): C[M,N] = A[M,K] * B[N,K]^T (+bias)(+relu)
// BM x BN tile, BK=32, 256 threads = 4 waves (2x2), 16x16x32 MFMA.
// A,B bf16 row-major K-contiguous. Output fp32 or bf16.
// ---------------------------------------------------------------------------
template <int BM, int BN, bool BIAS, bool RELU, bool OBF16>
__global__ __launch_bounds__(256) void gemm_bf16(
    const u16* __restrict__ A, const u16* __restrict__ B,
    const float* __restrict__ bias, float* __restrict__ Cf,
    u16* __restrict__ Cb, int M, int N, int K) {
  constexpr int MI = BM / 32, NI = BN / 32;
  __shared__ u16 As[BM * 32];
  __shared__ u16 Bs[BN * 32];
  const int tid = threadIdx.x;
  const int lane = tid & 63, wid = tid >> 6;
  const int row0 = blockIdx.y * BM, col0 = blockIdx.x * BN;
  const int wr = (wid >> 1) * (BM / 2), wc = (wid & 1) * (BN / 2);
  const int fr = lane & 15, hi = lane >> 4;

  f32x4 acc[MI][NI];
#pragma unroll
  for (int i = 0; i < MI; ++i)
#pragma unroll
    for (int j = 0; j < NI; ++j) acc[i][j] = {0.f, 0.f, 0.f, 0.f};

  const int sr = tid >> 2;       // staging row within 64-row chunk
  const int se = (tid & 3) * 8;  // staging k-element offset

  for (int k0 = 0; k0 < K; k0 += 32) {
#pragma unroll
    for (int c = 0; c < BM * 64; c += 4096) {
      const int r = (c >> 6) + sr;
      GLOAD16(A + (size_t)(row0 + r) * K + (k0 + se), ((char*)As) + c + tid * 16);
    }
#pragma unroll
    for (int c = 0; c < BN * 64; c += 4096) {
      const int r = (c >> 6) + sr;
      GLOAD16(B + (size_t)(col0 + r) * K + (k0 + se), ((char*)Bs) + c + tid * 16);
    }
    __syncthreads();  // drains vmcnt -> LDS tiles ready

    bf16x8 af[MI], bv[NI];
#pragma unroll
    for (int mi = 0; mi < MI; ++mi)
      af[mi] = *(const bf16x8*)&As[(wr + mi * 16 + fr) * 32 + hi * 8];
#pragma unroll
    for (int ni = 0; ni < NI; ++ni)
      bv[ni] = *(const bf16x8*)&Bs[(wc + ni * 16 + fr) * 32 + hi * 8];
#pragma unroll
    for (int mi = 0; mi < MI; ++mi)
#pragma unroll
      for (int ni = 0; ni < NI; ++ni)
        acc[mi][ni] = __builtin_amdgcn_mfma_f32_16x16x32_bf16(
            af[mi], bv[ni], acc[mi][ni], 0, 0, 0);
    __syncthreads();  // all reads done before next stage overwrites
  }

  // epilogue: C/D layout col=lane&15, row=(lane>>4)*4+j  [m89/m91 verified]
  const int erow = row0 + wr + (hi << 2);
  const int ecol0 = col0 + wc;
#pragma unroll
  for (int ni = 0; ni < NI; ++ni) {
    const int col = ecol0 + ni * 16 + fr;
    const float bvv = BIAS ? bias[col] : 0.f;
#pragma unroll
    for (int mi = 0; mi < MI; ++mi) {
      const int rbase = erow + mi * 16;
#pragma unroll
      for (int j = 0; j < 4; ++j) {
        float v = acc[mi][ni][j] + bvv;
        if (RELU) v = fmaxf(v, 0.f);
        const size_t idx = (size_t)(rbase + j) * N + col;
        if (OBF16) Cb[idx] = f2bf(v); else Cf[idx] = v;
      }
    }
  }
}

// ---------------------------------------------------------------------------
// Flash attention, fp32 compute, bf16 QKV input, KV-split x4 with partials.
// 1 thread per q-row per split. QKV packed [MROWS][3072]: Q|K|V.
// Partial record per (bh,q,split): 32 floats (64 bf16 acc) + m + l = 34 f.
// ---------------------------------------------------------------------------
__global__ __launch_bounds__(256) void attn_split(
    const u16* __restrict__ QKV, const int* __restrict__ mask,
    float* __restrict__ P) {
  constexpr int KB = 32, NSPL = 4, SPL = SEQ / NSPL;
  __shared__ float Kl[KB][DH];
  __shared__ float Vl[KB][DH];
  __shared__ int ml[KB];

  const int tid = threadIdx.x;
  const int qrow = blockIdx.x * 256 + tid;
  const int bh = blockIdx.y, sp = blockIdx.z;
  const int b = bh >> 4, h = bh & 15;
  const size_t base = (size_t)b * SEQ * 3072;

  const u16* qp = QKV + base + (size_t)qrow * 3072 + h * DH;
  float4 q[16];
#pragma unroll
  for (int i = 0; i < 8; ++i) {
    us8 u = *(const us8*)(qp + i * 8);
    q[2 * i] = make_float4(bf2f(u[0]), bf2f(u[1]), bf2f(u[2]), bf2f(u[3]));
    q[2 * i + 1] = make_float4(bf2f(u[4]), bf2f(u[5]), bf2f(u[6]), bf2f(u[7]));
  }
  float4 acc[16];
#pragma unroll
  for (int i = 0; i < 16; ++i) acc[i] = make_float4(0.f, 0.f, 0.f, 0.f);
  float m = -1e30f, l = 0.f;

  const int sr = tid >> 3, sc = (tid & 7) * 8;
  const u16* kpb = QKV + base + 1024 + h * DH + sc;
  const u16* vpb = QKV + base + 2048 + h * DH + sc;

  for (int kt = sp * SPL; kt < (sp + 1) * SPL; kt += KB) {
    us8 ku = *(const us8*)(kpb + (size_t)(kt + sr) * 3072);
    us8 vu = *(const us8*)(vpb + (size_t)(kt + sr) * 3072);
    __syncthreads();
#pragma unroll
    for (int e = 0; e < 8; ++e) {
      Kl[sr][sc + e] = bf2f(ku[e]);
      Vl[sr][sc + e] = bf2f(vu[e]);
    }
    if (tid < KB) ml[tid] = mask[b * SEQ + kt + tid];
    __syncthreads();

    float s[KB];
#pragma unroll
    for (int kk = 0; kk < KB; ++kk) {
      const float4* kr = (const float4*)Kl[kk];
      float sacc = 0.f;
#pragma unroll
      for (int i = 0; i < 16; ++i) {
        float4 kv = kr[i];
        sacc = fmaf(q[i].x, kv.x, sacc);
        sacc = fmaf(q[i].y, kv.y, sacc);
        sacc = fmaf(q[i].z, kv.z, sacc);
        sacc = fmaf(q[i].w, kv.w, sacc);
      }
      s[kk] = (ml[kk] == 0) ? -3e38f : sacc * 0.125f;
    }

    float tm = s[0];
#pragma unroll
    for (int kk = 1; kk < KB; ++kk) tm = fmaxf(tm, s[kk]);
    const float mn = fmaxf(m, tm);
    const float scale = __expf(m - mn);
    l *= scale;
#pragma unroll
    for (int i = 0; i < 16; ++i) {
      acc[i].x *= scale; acc[i].y *= scale;
      acc[i].z *= scale; acc[i].w *= scale;
    }
#pragma unroll
    for (int kk = 0; kk < KB; ++kk) {
      const float p = __expf(s[kk] - mn);
      l += p;
      const float4* vr = (const float4*)Vl[kk];
#pragma unroll
      for (int i = 0; i < 16; ++i) {
        float4 vv = vr[i];
        acc[i].x = fmaf(p, vv.x, acc[i].x);
        acc[i].y = fmaf(p, vv.y, acc[i].y);
        acc[i].z = fmaf(p, vv.z, acc[i].z);
        acc[i].w = fmaf(p, vv.w, acc[i].w);
      }
    }
    m = mn;
  }

  float* rec = P + ((size_t)(bh * SEQ + qrow) * NSPL + sp) * 34;
#pragma unroll
  for (int i = 0; i < 16; ++i) {
    unsigned int u0 = f2bf(acc[i].x) | ((unsigned)f2bf(acc[i].y) << 16);
    unsigned int u1 = f2bf(acc[i].z) | ((unsigned)f2bf(acc[i].w) << 16);
    rec[2 * i] = __uint_as_float(u0);
    rec[2 * i + 1] = __uint_as_float(u1);
  }
  rec[32] = m;
  rec[33] = l;
}

// ---------------------------------------------------------------------------
// Combine split partials -> bf16 O [MROWS][1024]. 64 lanes per (bh,q).
// ---------------------------------------------------------------------------
__global__ __launch_bounds__(256) void attn_combine(const float* __restrict__ P,
                                                    u16* __restrict__ Ob) {
  constexpr int NSPL = 4;
  const int tid = threadIdx.x;
  const int r = blockIdx.x * 4 + (tid >> 6);  // record index: bh*SEQ + q
  const int lane = tid & 63;
  const int bh = r >> 11, q = r & 2047;
  const int b = bh >> 4, h = bh & 15;
  const float* rec = P + (size_t)r * NSPL * 34;

  float ms[NSPL], ls[NSPL], av[NSPL];
  float M = -1e30f;
#pragma unroll
  for (int s = 0; s < NSPL; ++s) {
    ms[s] = rec[s * 34 + 32];
    ls[s] = rec[s * 34 + 33];
    unsigned int u = __float_as_uint(rec[s * 34 + (lane >> 1)]);
    av[s] = bf2f((u16)((lane & 1) ? (u >> 16) : (u & 0xffff)));
    M = fmaxf(M, ms[s]);
  }
  float O = 0.f, L = 0.f;
#pragma unroll
  for (int s = 0; s < NSPL; ++s) {
    const float w = __expf(ms[s] - M);
    O += w * av[s];
    L += w * ls[s];
  }
  Ob[((size_t)(b * SEQ + q)) * DM + h * DH + lane] = f2bf(O / L);
}

// ---------------------------------------------------------------------------
// Fused residual-add + LayerNorm. A: fp32 or bf16; B: fp32; out: fp32 or bf16.
// ---------------------------------------------------------------------------
template <bool ABF, bool OBF>
__global__ __launch_bounds__(256) void ln_add(const void* __restrict__ Ap,
                                              const float* __restrict__ Bx,
                                              const float* __restrict__ g,
                                              const float* __restrict__ be,
                                              void* __restrict__ outp) {
  __shared__ float red[2][4];
  __shared__ float mu_s, sig_s;
  const int row = blockIdx.x;
  const int tid = threadIdx.x;

  float4 a;
  if (ABF) {
    const u16* ap = (const u16*)Ap + (size_t)row * DM + tid * 4;
    const ushort4 u = *(const ushort4*)ap;
    a = make_float4(bf2f(u.x), bf2f(u.y), bf2f(u.z), bf2f(u.w));
  } else {
    a = *(const float4*)((const float*)Ap + (size_t)row * DM + tid * 4);
  }
  const float4 b = *(const float4*)(Bx + (size_t)row * DM + tid * 4);
  float4 s = make_float4(a.x + b.x, a.y + b.y, a.z + b.z, a.w + b.w);

  float sum = s.x + s.y + s.z + s.w;
  float sq = s.x * s.x + s.y * s.y + s.z * s.z + s.w * s.w;
#pragma unroll
  for (int off = 32; off >= 1; off >>= 1) {
    sum += __shfl_xor(sum, off);
    sq += __shfl_xor(sq, off);
  }
  const int wid = tid >> 6;
  if ((tid & 63) == 0) { red[0][wid] = sum; red[1][wid] = sq; }
  __syncthreads();
  if (tid == 0) {
    float ts = red[0][0] + red[0][1] + red[0][2] + red[0][3];
    float tq = red[1][0] + red[1][1] + red[1][2] + red[1][3];
    float mu = ts * (1.f / DM);
    float var = tq * (1.f / DM) - mu * mu;
    mu_s = mu;
    sig_s = sqrtf(fmaxf(var, 0.f)) + 1e-6f;
  }
  __syncthreads();
  const float mu = mu_s, inv = 1.f / sig_s;
  const float4 gv = *(const float4*)(g + tid * 4);
  const float4 bv = *(const float4*)(be + tid * 4);
  float4 o;
  o.x = (s.x - mu) * inv * gv.x + bv.x;
  o.y = (s.y - mu) * inv * gv.y + bv.y;
  o.z = (s.z - mu) * inv * gv.z + bv.z;
  o.w = (s.w - mu) * inv * gv.w + bv.w;
  if (OBF) {
    u16* op = (u16*)outp + (size_t)row * DM + tid * 4;
    ushort4 o4;
    o4.x = f2bf(o.x); o4.y = f2bf(o.y); o4.z = f2bf(o.z); o4.w = f2bf(o.w);
    *(ushort4*)op = o4;
  } else {
    *(float4*)((float*)outp + (size_t)row * DM + tid * 4) = o;
  }
}

// ---------------------------------------------------------------------------
extern "C" void kernel_launch(void* const* d_in, const int* in_sizes, int n_in,
                              void* d_out, int out_size, void* d_ws,
                              size_t ws_size, hipStream_t stream) {
  const float* x  = (const float*)d_in[0];
  const int* mask = (const int*)d_in[1];
  const float* Wq = (const float*)d_in[2];
  const float* Wk = (const float*)d_in[3];
  const float* Wv = (const float*)d_in[4];
  const float* Wo = (const float*)d_in[5];
  const float* w1 = (const float*)d_in[6];
  const float* b1 = (const float*)d_in[7];
  const float* w2 = (const float*)d_in[8];
  const float* b2 = (const float*)d_in[9];
  const float* g1 = (const float*)d_in[10];
  const float* be1 = (const float*)d_in[11];
  const float* g2 = (const float*)d_in[12];
  const float* be2 = (const float*)d_in[13];
  float* out = (float*)d_out;
  float* ws = (float*)d_ws;

  // workspace layout (float offsets) — NO overlaps among live ranges:
  //  QKVb  [0        .. 6291456)   4096x3072 bf16
  //  xb    [6291456  .. 8388608)   4096x1024 bf16
  //  Wqkvb [8388608  .. 9961472)   3072x1024 bf16
  //  Wob   [9961472  .. 10485760)  1024x1024 bf16
  //  w1b   [10485760 .. 12582912)  4096x1024 bf16
  //  w2b   [12582912 .. 14680064)  1024x4096 bf16
  //  Obf   [14680064 .. 16777216)  4096x1024 bf16
  //  P     [16777216 .. 25690112)  65536*4*34 f32   (dead after combine)
  //  X1    [16777216 .. 20971520)  4096x1024 f32    (reuses P head)
  //  X2b   [20971520 .. 23068672)  4096x1024 bf16   (reuses P tail)
  //  X3    [23068672 .. 27262976)  4096x1024 f32
  //  Hb    [0        .. 8388608)   4096x4096 bf16   (reuses QKVb+xb, dead)
  u16*   QKVb  = (u16*)(ws + 0);
  u16*   xb    = (u16*)(ws + 6291456);
  u16*   Wqkvb = (u16*)(ws + 8388608);
  u16*   Wob   = (u16*)(ws + 9961472);
  u16*   w1b   = (u16*)(ws + 10485760);
  u16*   w2b   = (u16*)(ws + 12582912);
  u16*   Obf   = (u16*)(ws + 14680064);
  float* P     = ws + 16777216;
  float* X1    = ws + 16777216;
  u16*   X2b   = (u16*)(ws + 20971520);
  float* X3    = ws + 23068672;
  u16*   Hb    = (u16*)(ws + 0);

  const dim3 blk(256);

  // fp32 -> bf16 converts
  cvt_bf16<<<2048, blk, 0, stream>>>(x, xb, MROWS * DM);
  cvt_bf16<<<512,  blk, 0, stream>>>(Wq, Wqkvb, DM * DM);
  cvt_bf16<<<512,  blk, 0, stream>>>(Wk, Wqkvb + DM * DM, DM * DM);
  cvt_bf16<<<512,  blk, 0, stream>>>(Wv, Wqkvb + 2 * DM * DM, DM * DM);
  cvt_bf16<<<512,  blk, 0, stream>>>(Wo, Wob, DM * DM);
  cvt_bf16<<<2048, blk, 0, stream>>>(w1, w1b, DFF * DM);
  cvt_bf16<<<2048, blk, 0, stream>>>(w2, w2b, DM * DFF);

  // fused QKV projection: [4096,3072] = xb @ Wqkvb^T, bf16 out
  gemm_bf16<128, 128, false, false, true><<<dim3(3072 / 128, MROWS / 128), blk, 0, stream>>>(
      xb, Wqkvb, nullptr, nullptr, QKVb, MROWS, 3072, DM);

  // attention (KV-split x4) + combine
  attn_split<<<dim3(SEQ / 256, BSZ * NH, 4), blk, 0, stream>>>(QKVb, mask, P);
  attn_combine<<<dim3(BSZ * NH * SEQ / 4), blk, 0, stream>>>(P, Obf);

  // X1 = O @ Wo^T (fp32 out), 64x128 tiles for occupancy on thin N
  gemm_bf16<64, 128, false, false, false><<<dim3(DM / 128, MROWS / 64), blk, 0, stream>>>(
      Obf, Wob, nullptr, X1, nullptr, MROWS, DM, DM);

  // X2 = LN(X1 + x) -> bf16
  ln_add<false, true><<<dim3(MROWS), blk, 0, stream>>>(X1, x, g1, be1, X2b);

  // H = relu(X2 @ w1^T + b1) -> bf16
  gemm_bf16<128, 128, true, true, true><<<dim3(DFF / 128, MROWS / 128), blk, 0, stream>>>(
      X2b, w1b, b1, nullptr, Hb, MROWS, DFF, DM);

  // X3 = H @ w2^T + b2 -> fp32
  gemm_bf16<64, 128, true, false, false><<<dim3(DM / 128, MROWS / 64), blk, 0, stream>>>(
      Hb, w2b, b2, X3, nullptr, MROWS, DM, DFF);

  // out = LN(X2 + X3)
  ln_add<true, false><<<dim3(MROWS), blk, 0, stream>>>(X2b, X3, g2, be2, out);
}

// Round 4
// 401.233 us; speedup vs baseline: 5.9955x; 3.9325x over previous
//
#include <hip/hip_runtime.h>
#include <math.h>

typedef __attribute__((ext_vector_type(8))) short bf16x8;
typedef __attribute__((ext_vector_type(4))) float f32x4;
typedef __attribute__((ext_vector_type(8))) unsigned short us8;
typedef unsigned short u16;

constexpr int BSZ = 2, SEQ = 2048, DM = 1024, DFF = 4096, NH = 16, DH = 64;
constexpr int MROWS = BSZ * SEQ;  // 4096

__device__ __forceinline__ float bf2f(u16 u) {
  union { unsigned int i; float f; } v; v.i = ((unsigned int)u) << 16; return v.f;
}
__device__ __forceinline__ u16 f2bf(float f) {
  union { float f; unsigned int i; } v; v.f = f;
  unsigned int r = v.i + 0x7fffu + ((v.i >> 16) & 1u);
  return (u16)(r >> 16);
}

#define GLOAD16(gp, lp) __builtin_amdgcn_global_load_lds( \
    (const __attribute__((address_space(1))) void*)(gp),  \
    (__attribute__((address_space(3))) void*)(lp), 16, 0, 0)

// ---------------------------------------------------------------------------
// fp32 -> bf16 convert (RNE), 8 elements/thread
// ---------------------------------------------------------------------------
__global__ __launch_bounds__(256) void cvt_bf16(const float* __restrict__ in,
                                                u16* __restrict__ out, int n) {
  const int i = (blockIdx.x * 256 + threadIdx.x) * 8;
  if (i >= n) return;
  const float4 a = *(const float4*)(in + i);
  const float4 b = *(const float4*)(in + i + 4);
  uint4 o;
  o.x = f2bf(a.x) | ((unsigned)f2bf(a.y) << 16);
  o.y = f2bf(a.z) | ((unsigned)f2bf(a.w) << 16);
  o.z = f2bf(b.x) | ((unsigned)f2bf(b.y) << 16);
  o.w = f2bf(b.z) | ((unsigned)f2bf(b.w) << 16);
  *(uint4*)(out + i) = o;
}

// ---------------------------------------------------------------------------
// bf16 MFMA GEMM (m97 structure): C[M,N] = A[M,K] * B[N,K]^T (+bias)(+relu)
// ---------------------------------------------------------------------------
template <int BM, int BN, bool BIAS, bool RELU, bool OBF16>
__global__ __launch_bounds__(256) void gemm_bf16(
    const u16* __restrict__ A, const u16* __restrict__ B,
    const float* __restrict__ bias, float* __restrict__ Cf,
    u16* __restrict__ Cb, int M, int N, int K) {
  constexpr int MI = BM / 32, NI = BN / 32;
  __shared__ u16 As[BM * 32];
  __shared__ u16 Bs[BN * 32];
  const int tid = threadIdx.x;
  const int lane = tid & 63, wid = tid >> 6;
  const int row0 = blockIdx.y * BM, col0 = blockIdx.x * BN;
  const int wr = (wid >> 1) * (BM / 2), wc = (wid & 1) * (BN / 2);
  const int fr = lane & 15, hi = lane >> 4;

  f32x4 acc[MI][NI];
#pragma unroll
  for (int i = 0; i < MI; ++i)
#pragma unroll
    for (int j = 0; j < NI; ++j) acc[i][j] = {0.f, 0.f, 0.f, 0.f};

  const int sr = tid >> 2;       // staging row within 64-row chunk
  const int se = (tid & 3) * 8;  // staging k-element offset

  for (int k0 = 0; k0 < K; k0 += 32) {
#pragma unroll
    for (int c = 0; c < BM * 64; c += 4096) {
      const int r = (c >> 6) + sr;
      GLOAD16(A + (size_t)(row0 + r) * K + (k0 + se), ((char*)As) + c + tid * 16);
    }
#pragma unroll
    for (int c = 0; c < BN * 64; c += 4096) {
      const int r = (c >> 6) + sr;
      GLOAD16(B + (size_t)(col0 + r) * K + (k0 + se), ((char*)Bs) + c + tid * 16);
    }
    __syncthreads();

    bf16x8 af[MI], bv[NI];
#pragma unroll
    for (int mi = 0; mi < MI; ++mi)
      af[mi] = *(const bf16x8*)&As[(wr + mi * 16 + fr) * 32 + hi * 8];
#pragma unroll
    for (int ni = 0; ni < NI; ++ni)
      bv[ni] = *(const bf16x8*)&Bs[(wc + ni * 16 + fr) * 32 + hi * 8];
#pragma unroll
    for (int mi = 0; mi < MI; ++mi)
#pragma unroll
      for (int ni = 0; ni < NI; ++ni)
        acc[mi][ni] = __builtin_amdgcn_mfma_f32_16x16x32_bf16(
            af[mi], bv[ni], acc[mi][ni], 0, 0, 0);
    __syncthreads();
  }

  const int erow = row0 + wr + (hi << 2);
  const int ecol0 = col0 + wc;
#pragma unroll
  for (int ni = 0; ni < NI; ++ni) {
    const int col = ecol0 + ni * 16 + fr;
    const float bvv = BIAS ? bias[col] : 0.f;
#pragma unroll
    for (int mi = 0; mi < MI; ++mi) {
      const int rbase = erow + mi * 16;
#pragma unroll
      for (int j = 0; j < 4; ++j) {
        float v = acc[mi][ni][j] + bvv;
        if (RELU) v = fmaxf(v, 0.f);
        const size_t idx = (size_t)(rbase + j) * N + col;
        if (OBF16) Cb[idx] = f2bf(v); else Cf[idx] = v;
      }
    }
  }
}

// ---------------------------------------------------------------------------
// MFMA flash attention. 4 waves/block; wave owns 16 q-rows. QBLK=64, KB=64.
// QKV packed [B*SEQ][3072] bf16 (Q|K|V), head h at +h*64.
// K_lds swizzled rows (byte ^= (row&7)<<4); V staged transposed Vt[d][k],
// same swizzle; P per-wave in swizzled LDS for the PV A-fragment.
// S tile via mfma(Q,K): lane holds S[q=(lane>>4)*4+j][k=t16*16+(lane&15)].
// ---------------------------------------------------------------------------
__global__ __launch_bounds__(256) void attn_mfma(
    const u16* __restrict__ QKV, const int* __restrict__ mask,
    u16* __restrict__ Ob) {
  constexpr int KB = 64, QB = 64;
  __shared__ u16 Kl[KB * 64];       // [k][d], swizzled, 8 KB
  __shared__ u16 Vt[64 * KB];       // [d][k], swizzled, 8 KB
  __shared__ u16 Pl[4][16 * 64];    // per-wave P [q][k], swizzled, 8 KB
  __shared__ int ml[KB];

  const int tid = threadIdx.x;
  const int lane = tid & 63, wid = tid >> 6;
  const int q0 = blockIdx.x * QB;
  const int bh = blockIdx.y;
  const int b = bh >> 4, h = bh & 15;
  const size_t base = (size_t)b * SEQ * 3072;

  const int fr = lane & 15, g = lane >> 4;

  // Q fragments (A-operand): row q = wid*16 + fr, k-elems d = g*8..+8 (+32)
  const u16* qp = QKV + base + (size_t)(q0 + wid * 16 + fr) * 3072 + h * 64 + g * 8;
  const bf16x8 qf0 = *(const bf16x8*)qp;
  const bf16x8 qf1 = *(const bf16x8*)(qp + 32);

  f32x4 o[4] = {{0.f,0.f,0.f,0.f},{0.f,0.f,0.f,0.f},{0.f,0.f,0.f,0.f},{0.f,0.f,0.f,0.f}};
  float mreg[4] = {-3e38f, -3e38f, -3e38f, -3e38f};
  float lreg[4] = {0.f, 0.f, 0.f, 0.f};

  const int skr = tid >> 3;      // staging row 0..31 per pass
  const int skc = tid & 7;       // 16B chunk within row

  for (int kt = 0; kt < SEQ; kt += KB) {
    __syncthreads();  // prev-iter LDS reads done before overwrite
#pragma unroll
    for (int p = 0; p < 2; ++p) {
      const int r = p * 32 + skr;  // k-row within tile
      const us8 kv = *(const us8*)(QKV + base + (size_t)(kt + r) * 3072 + 1024 + h * 64 + skc * 8);
      *(us8*)((char*)Kl + r * 128 + ((skc * 16) ^ ((r & 7) << 4))) = kv;
      const us8 vv = *(const us8*)(QKV + base + (size_t)(kt + r) * 3072 + 2048 + h * 64 + skc * 8);
#pragma unroll
      for (int i = 0; i < 8; ++i) {
        const int d = skc * 8 + i;  // d&7 == i
        *(u16*)((char*)Vt + d * 128 + ((2 * r) ^ (i << 4))) = vv[i];
      }
    }
    if (tid < 16) *(int4*)&ml[tid * 4] = *(const int4*)&mask[b * SEQ + kt + tid * 4];
    __syncthreads();

    // S = Q K^T for 4 k-subtiles
    f32x4 s[4];
#pragma unroll
    for (int t16 = 0; t16 < 4; ++t16) {
      const int kr = t16 * 16 + fr;
      const char* krow = (const char*)Kl + kr * 128;
      const int sw = (kr & 7) << 4;
      const bf16x8 kf0 = *(const bf16x8*)(krow + ((g * 16) ^ sw));
      const bf16x8 kf1 = *(const bf16x8*)(krow + ((g * 16 + 64) ^ sw));
      f32x4 a = {0.f, 0.f, 0.f, 0.f};
      a = __builtin_amdgcn_mfma_f32_16x16x32_bf16(qf0, kf0, a, 0, 0, 0);
      a = __builtin_amdgcn_mfma_f32_16x16x32_bf16(qf1, kf1, a, 0, 0, 0);
      s[t16] = a;
    }

    // scale + mask
#pragma unroll
    for (int t16 = 0; t16 < 4; ++t16) {
      const int mv = ml[t16 * 16 + fr];
#pragma unroll
      for (int j = 0; j < 4; ++j)
        s[t16][j] = (mv == 0) ? -3e38f : s[t16][j] * 0.125f;
    }

    // row max across k (4 regs + 16-lane group butterfly)
    float rmax[4];
#pragma unroll
    for (int j = 0; j < 4; ++j)
      rmax[j] = fmaxf(fmaxf(s[0][j], s[1][j]), fmaxf(s[2][j], s[3][j]));
#pragma unroll
    for (int off = 1; off <= 8; off <<= 1)
#pragma unroll
      for (int j = 0; j < 4; ++j)
        rmax[j] = fmaxf(rmax[j], __shfl_xor(rmax[j], off));

    // online-softmax update
    float sc[4];
#pragma unroll
    for (int j = 0; j < 4; ++j) {
      const float mn = fmaxf(mreg[j], rmax[j]);
      sc[j] = __expf(mreg[j] - mn);
      mreg[j] = mn;
      lreg[j] *= sc[j];
    }
#pragma unroll
    for (int dt = 0; dt < 4; ++dt)
#pragma unroll
      for (int j = 0; j < 4; ++j) o[dt][j] *= sc[j];

#pragma unroll
    for (int t16 = 0; t16 < 4; ++t16)
#pragma unroll
      for (int j = 0; j < 4; ++j)
        s[t16][j] = __expf(s[t16][j] - mreg[j]);

    float rsum[4];
#pragma unroll
    for (int j = 0; j < 4; ++j)
      rsum[j] = (s[0][j] + s[1][j]) + (s[2][j] + s[3][j]);
#pragma unroll
    for (int off = 1; off <= 8; off <<= 1)
#pragma unroll
      for (int j = 0; j < 4; ++j)
        rsum[j] += __shfl_xor(rsum[j], off);
#pragma unroll
    for (int j = 0; j < 4; ++j) lreg[j] += rsum[j];

    // P -> per-wave LDS (bf16, swizzled)
    char* pw = (char*)Pl[wid];
#pragma unroll
    for (int t16 = 0; t16 < 4; ++t16) {
      const int kc = t16 * 16 + fr;
#pragma unroll
      for (int j = 0; j < 4; ++j) {
        const int q = g * 4 + j;
        *(u16*)(pw + q * 128 + ((2 * kc) ^ ((q & 7) << 4))) = f2bf(s[t16][j]);
      }
    }
    asm volatile("s_waitcnt lgkmcnt(0)" ::: "memory");
    __builtin_amdgcn_sched_barrier(0);

    // O += P V : A = P[16q][32k] (row=fr), B = Vt (col d = dt*16+fr)
#pragma unroll
    for (int kh = 0; kh < 2; ++kh) {
      const bf16x8 pf = *(const bf16x8*)(pw + fr * 128 + ((g * 16 + kh * 64) ^ ((fr & 7) << 4)));
#pragma unroll
      for (int dt = 0; dt < 4; ++dt) {
        const int d = dt * 16 + fr;
        const bf16x8 vf = *(const bf16x8*)((const char*)Vt + d * 128 + ((g * 16 + kh * 64) ^ ((d & 7) << 4)));
        o[dt] = __builtin_amdgcn_mfma_f32_16x16x32_bf16(pf, vf, o[dt], 0, 0, 0);
      }
    }
  }

  // epilogue: O[q][d] / l, q = q0 + wid*16 + g*4 + j, d = dt*16 + fr
#pragma unroll
  for (int j = 0; j < 4; ++j) {
    const float inv = 1.f / lreg[j];
    const int qrow = q0 + wid * 16 + g * 4 + j;
    u16* orow = Ob + (size_t)(b * SEQ + qrow) * DM + h * 64;
#pragma unroll
    for (int dt = 0; dt < 4; ++dt)
      orow[dt * 16 + fr] = f2bf(o[dt][j] * inv);
  }
}

// ---------------------------------------------------------------------------
// Fused residual-add + LayerNorm. A: fp32 or bf16; B: fp32; out: fp32 or bf16.
// ---------------------------------------------------------------------------
template <bool ABF, bool OBF>
__global__ __launch_bounds__(256) void ln_add(const void* __restrict__ Ap,
                                              const float* __restrict__ Bx,
                                              const float* __restrict__ g,
                                              const float* __restrict__ be,
                                              void* __restrict__ outp) {
  __shared__ float red[2][4];
  __shared__ float mu_s, sig_s;
  const int row = blockIdx.x;
  const int tid = threadIdx.x;

  float4 a;
  if (ABF) {
    const u16* ap = (const u16*)Ap + (size_t)row * DM + tid * 4;
    const ushort4 u = *(const ushort4*)ap;
    a = make_float4(bf2f(u.x), bf2f(u.y), bf2f(u.z), bf2f(u.w));
  } else {
    a = *(const float4*)((const float*)Ap + (size_t)row * DM + tid * 4);
  }
  const float4 b = *(const float4*)(Bx + (size_t)row * DM + tid * 4);
  float4 s = make_float4(a.x + b.x, a.y + b.y, a.z + b.z, a.w + b.w);

  float sum = s.x + s.y + s.z + s.w;
  float sq = s.x * s.x + s.y * s.y + s.z * s.z + s.w * s.w;
#pragma unroll
  for (int off = 32; off >= 1; off >>= 1) {
    sum += __shfl_xor(sum, off);
    sq += __shfl_xor(sq, off);
  }
  const int wid = tid >> 6;
  if ((tid & 63) == 0) { red[0][wid] = sum; red[1][wid] = sq; }
  __syncthreads();
  if (tid == 0) {
    float ts = red[0][0] + red[0][1] + red[0][2] + red[0][3];
    float tq = red[1][0] + red[1][1] + red[1][2] + red[1][3];
    float mu = ts * (1.f / DM);
    float var = tq * (1.f / DM) - mu * mu;
    mu_s = mu;
    sig_s = sqrtf(fmaxf(var, 0.f)) + 1e-6f;
  }
  __syncthreads();
  const float mu = mu_s, inv = 1.f / sig_s;
  const float4 gv = *(const float4*)(g + tid * 4);
  const float4 bv = *(const float4*)(be + tid * 4);
  float4 o;
  o.x = (s.x - mu) * inv * gv.x + bv.x;
  o.y = (s.y - mu) * inv * gv.y + bv.y;
  o.z = (s.z - mu) * inv * gv.z + bv.z;
  o.w = (s.w - mu) * inv * gv.w + bv.w;
  if (OBF) {
    u16* op = (u16*)outp + (size_t)row * DM + tid * 4;
    ushort4 o4;
    o4.x = f2bf(o.x); o4.y = f2bf(o.y); o4.z = f2bf(o.z); o4.w = f2bf(o.w);
    *(ushort4*)op = o4;
  } else {
    *(float4*)((float*)outp + (size_t)row * DM + tid * 4) = o;
  }
}

// ---------------------------------------------------------------------------
extern "C" void kernel_launch(void* const* d_in, const int* in_sizes, int n_in,
                              void* d_out, int out_size, void* d_ws,
                              size_t ws_size, hipStream_t stream) {
  const float* x  = (const float*)d_in[0];
  const int* mask = (const int*)d_in[1];
  const float* Wq = (const float*)d_in[2];
  const float* Wk = (const float*)d_in[3];
  const float* Wv = (const float*)d_in[4];
  const float* Wo = (const float*)d_in[5];
  const float* w1 = (const float*)d_in[6];
  const float* b1 = (const float*)d_in[7];
  const float* w2 = (const float*)d_in[8];
  const float* b2 = (const float*)d_in[9];
  const float* g1 = (const float*)d_in[10];
  const float* be1 = (const float*)d_in[11];
  const float* g2 = (const float*)d_in[12];
  const float* be2 = (const float*)d_in[13];
  float* out = (float*)d_out;
  float* ws = (float*)d_ws;

  // workspace layout (float offsets) — no overlaps among live ranges:
  //  QKVb  [0        .. 6291456)   4096x3072 bf16
  //  xb    [6291456  .. 8388608)   4096x1024 bf16
  //  Wqkvb [8388608  .. 9961472)   3072x1024 bf16
  //  Wob   [9961472  .. 10485760)  1024x1024 bf16
  //  w1b   [10485760 .. 12582912)  4096x1024 bf16
  //  w2b   [12582912 .. 14680064)  1024x4096 bf16
  //  Obf   [14680064 .. 16777216)  4096x1024 bf16
  //  X1    [16777216 .. 20971520)  4096x1024 f32
  //  X2b   [20971520 .. 23068672)  4096x1024 bf16
  //  X3    [23068672 .. 27262976)  4096x1024 f32
  //  Hb    [0        .. 8388608)   4096x4096 bf16 (reuses QKVb+xb, dead then)
  u16*   QKVb  = (u16*)(ws + 0);
  u16*   xb    = (u16*)(ws + 6291456);
  u16*   Wqkvb = (u16*)(ws + 8388608);
  u16*   Wob   = (u16*)(ws + 9961472);
  u16*   w1b   = (u16*)(ws + 10485760);
  u16*   w2b   = (u16*)(ws + 12582912);
  u16*   Obf   = (u16*)(ws + 14680064);
  float* X1    = ws + 16777216;
  u16*   X2b   = (u16*)(ws + 20971520);
  float* X3    = ws + 23068672;
  u16*   Hb    = (u16*)(ws + 0);

  const dim3 blk(256);

  cvt_bf16<<<2048, blk, 0, stream>>>(x, xb, MROWS * DM);
  cvt_bf16<<<512,  blk, 0, stream>>>(Wq, Wqkvb, DM * DM);
  cvt_bf16<<<512,  blk, 0, stream>>>(Wk, Wqkvb + DM * DM, DM * DM);
  cvt_bf16<<<512,  blk, 0, stream>>>(Wv, Wqkvb + 2 * DM * DM, DM * DM);
  cvt_bf16<<<512,  blk, 0, stream>>>(Wo, Wob, DM * DM);
  cvt_bf16<<<2048, blk, 0, stream>>>(w1, w1b, DFF * DM);
  cvt_bf16<<<2048, blk, 0, stream>>>(w2, w2b, DM * DFF);

  // fused QKV projection: [4096,3072] = xb @ Wqkvb^T, bf16 out
  gemm_bf16<128, 128, false, false, true><<<dim3(3072 / 128, MROWS / 128), blk, 0, stream>>>(
      xb, Wqkvb, nullptr, nullptr, QKVb, MROWS, 3072, DM);

  // MFMA flash attention -> Obf
  attn_mfma<<<dim3(SEQ / 64, BSZ * NH), blk, 0, stream>>>(QKVb, mask, Obf);

  // X1 = O @ Wo^T (fp32 out)
  gemm_bf16<64, 128, false, false, false><<<dim3(DM / 128, MROWS / 64), blk, 0, stream>>>(
      Obf, Wob, nullptr, X1, nullptr, MROWS, DM, DM);

  // X2 = LN(X1 + x) -> bf16
  ln_add<false, true><<<dim3(MROWS), blk, 0, stream>>>(X1, x, g1, be1, X2b);

  // H = relu(X2 @ w1^T + b1) -> bf16
  gemm_bf16<128, 128, true, true, true><<<dim3(DFF / 128, MROWS / 128), blk, 0, stream>>>(
      X2b, w1b, b1, nullptr, Hb, MROWS, DFF, DM);

  // X3 = H @ w2^T + b2 -> fp32
  gemm_bf16<64, 128, true, false, false><<<dim3(DM / 128, MROWS / 64), blk, 0, stream>>>(
      Hb, w2b, b2, X3, nullptr, MROWS, DM, DFF);

  // out = LN(X2 + X3)
  ln_add<true, false><<<dim3(MROWS), blk, 0, stream>>>(X2b, X3, g2, be2, out);
}

// Round 5
// 379.128 us; speedup vs baseline: 6.3451x; 1.0583x over previous
//
#include <hip/hip_runtime.h>
#include <math.h>

typedef __attribute__((ext_vector_type(8))) short bf16x8;
typedef __attribute__((ext_vector_type(4))) float f32x4;
typedef __attribute__((ext_vector_type(8))) unsigned short us8;
typedef unsigned short u16;
typedef unsigned int u32;

constexpr int BSZ = 2, SEQ = 2048, DM = 1024, DFF = 4096, NH = 16, DH = 64;
constexpr int MROWS = BSZ * SEQ;  // 4096

__device__ __forceinline__ float bf2f(u16 u) {
  union { unsigned int i; float f; } v; v.i = ((unsigned int)u) << 16; return v.f;
}
__device__ __forceinline__ u16 f2bf(float f) {
  union { float f; unsigned int i; } v; v.f = f;
  unsigned int r = v.i + 0x7fffu + ((v.i >> 16) & 1u);
  return (u16)(r >> 16);
}

#define GLOAD16(gp, lp) __builtin_amdgcn_global_load_lds( \
    (const __attribute__((address_space(1))) void*)(gp),  \
    (__attribute__((address_space(3))) void*)(lp), 16, 0, 0)
#define GLOAD4(gp, lp) __builtin_amdgcn_global_load_lds( \
    (const __attribute__((address_space(1))) void*)(gp),  \
    (__attribute__((address_space(3))) void*)(lp), 4, 0, 0)

// ---------------------------------------------------------------------------
// fp32 -> bf16 convert (RNE), 8 elements/thread
// ---------------------------------------------------------------------------
__global__ __launch_bounds__(256) void cvt_bf16(const float* __restrict__ in,
                                                u16* __restrict__ out, int n) {
  const int i = (blockIdx.x * 256 + threadIdx.x) * 8;
  if (i >= n) return;
  const float4 a = *(const float4*)(in + i);
  const float4 b = *(const float4*)(in + i + 4);
  uint4 o;
  o.x = f2bf(a.x) | ((unsigned)f2bf(a.y) << 16);
  o.y = f2bf(a.z) | ((unsigned)f2bf(a.w) << 16);
  o.z = f2bf(b.x) | ((unsigned)f2bf(b.y) << 16);
  o.w = f2bf(b.z) | ((unsigned)f2bf(b.w) << 16);
  *(uint4*)(out + i) = o;
}

// ---------------------------------------------------------------------------
// bf16 MFMA GEMM (m97 structure): C[M,N] = A[M,K] * B[N,K]^T (+bias)(+relu)
// ---------------------------------------------------------------------------
template <int BM, int BN, bool BIAS, bool RELU, bool OBF16>
__global__ __launch_bounds__(256) void gemm_bf16(
    const u16* __restrict__ A, const u16* __restrict__ B,
    const float* __restrict__ bias, float* __restrict__ Cf,
    u16* __restrict__ Cb, int M, int N, int K) {
  constexpr int MI = BM / 32, NI = BN / 32;
  __shared__ u16 As[BM * 32];
  __shared__ u16 Bs[BN * 32];
  const int tid = threadIdx.x;
  const int lane = tid & 63, wid = tid >> 6;
  const int row0 = blockIdx.y * BM, col0 = blockIdx.x * BN;
  const int wr = (wid >> 1) * (BM / 2), wc = (wid & 1) * (BN / 2);
  const int fr = lane & 15, hi = lane >> 4;

  f32x4 acc[MI][NI];
#pragma unroll
  for (int i = 0; i < MI; ++i)
#pragma unroll
    for (int j = 0; j < NI; ++j) acc[i][j] = {0.f, 0.f, 0.f, 0.f};

  const int sr = tid >> 2;       // staging row within 64-row chunk
  const int se = (tid & 3) * 8;  // staging k-element offset

  for (int k0 = 0; k0 < K; k0 += 32) {
#pragma unroll
    for (int c = 0; c < BM * 64; c += 4096) {
      const int r = (c >> 6) + sr;
      GLOAD16(A + (size_t)(row0 + r) * K + (k0 + se), ((char*)As) + c + tid * 16);
    }
#pragma unroll
    for (int c = 0; c < BN * 64; c += 4096) {
      const int r = (c >> 6) + sr;
      GLOAD16(B + (size_t)(col0 + r) * K + (k0 + se), ((char*)Bs) + c + tid * 16);
    }
    __syncthreads();

    bf16x8 af[MI], bv[NI];
#pragma unroll
    for (int mi = 0; mi < MI; ++mi)
      af[mi] = *(const bf16x8*)&As[(wr + mi * 16 + fr) * 32 + hi * 8];
#pragma unroll
    for (int ni = 0; ni < NI; ++ni)
      bv[ni] = *(const bf16x8*)&Bs[(wc + ni * 16 + fr) * 32 + hi * 8];
#pragma unroll
    for (int mi = 0; mi < MI; ++mi)
#pragma unroll
      for (int ni = 0; ni < NI; ++ni)
        acc[mi][ni] = __builtin_amdgcn_mfma_f32_16x16x32_bf16(
            af[mi], bv[ni], acc[mi][ni], 0, 0, 0);
    __syncthreads();
  }

  const int erow = row0 + wr + (hi << 2);
  const int ecol0 = col0 + wc;
#pragma unroll
  for (int ni = 0; ni < NI; ++ni) {
    const int col = ecol0 + ni * 16 + fr;
    const float bvv = BIAS ? bias[col] : 0.f;
#pragma unroll
    for (int mi = 0; mi < MI; ++mi) {
      const int rbase = erow + mi * 16;
#pragma unroll
      for (int j = 0; j < 4; ++j) {
        float v = acc[mi][ni][j] + bvv;
        if (RELU) v = fmaxf(v, 0.f);
        const size_t idx = (size_t)(rbase + j) * N + col;
        if (OBF16) Cb[idx] = f2bf(v); else Cf[idx] = v;
      }
    }
  }
}

// ---------------------------------------------------------------------------
// MFMA flash attention v2. 4 waves/block, wave owns 16 q-rows. QB=KB=64.
// - K double-buffered via global_load_lds, source pre-swizzled (chunk^=(k&7))
//   so swizzled reads are conflict-free (ERRATA#21 both-sides involution).
// - V double-buffered, staged transposed Vt[d][k] (scalar stores, swizzled).
// - Swapped QK^T: S^T = mfma(K, Q) -> lane (fr,g) holds S[k=t16*16+g*4+j][q=fr]
//   => softmax stats are per-lane scalars (2-step butterfly over g-bits).
// - P stays in registers: bf16-pack + 16 dword shfls build the PV A-fragment.
// - One barrier per iter; prefetch in flight across compute (2-phase T3).
// ---------------------------------------------------------------------------
__global__ __launch_bounds__(256) void attn_mfma(
    const u16* __restrict__ QKV, const int* __restrict__ mask,
    u16* __restrict__ Ob) {
  constexpr int KB = 64, QB = 64, NT = SEQ / KB;
  __shared__ u16 Kl[2][KB * 64];   // [k][d] rows 128B, chunk^=(k&7) swizzle
  __shared__ u16 Vt[2][64 * KB];   // [d][k] rows 128B, byte 2k ^ ((d&7)<<4)
  __shared__ int ml[2][KB];

  const int tid = threadIdx.x;
  const int lane = tid & 63, wid = tid >> 6;
  const int q0 = blockIdx.x * QB;
  const int bh = blockIdx.y;
  const int b = bh >> 4, h = bh & 15;
  const size_t base = (size_t)b * SEQ * 3072;
  const int fr = lane & 15, g = lane >> 4;

  // Q fragment (B-operand): row q = q0+wid*16+fr, elems d = g*8..+8 (+32)
  const u16* qp = QKV + base + (size_t)(q0 + wid * 16 + fr) * 3072 + h * 64 + g * 8;
  const bf16x8 qf0 = *(const bf16x8*)qp;
  const bf16x8 qf1 = *(const bf16x8*)(qp + 32);

  // K staging (global_load_lds, pre-swizzled source)
  const int krow = wid * 16 + (lane >> 3);          // +n*8 per instruction
  const int kcol = 8 * ((lane & 7) ^ (lane >> 3));  // inverse-swizzled chunk
  const u16* ksrc = QKV + base + 1024 + h * 64 + kcol;
  const int kdst = wid * 2048 + lane * 16;          // byte offset in K buffer

  // V staging (scalar transposed)
  const int skr = tid >> 3, skc = tid & 7;
  const u16* vsrc = QKV + base + 2048 + h * 64 + skc * 8;

  f32x4 o[4] = {{0.f,0.f,0.f,0.f},{0.f,0.f,0.f,0.f},{0.f,0.f,0.f,0.f},{0.f,0.f,0.f,0.f}};
  float mreg = -3e38f, lreg = 0.f;

  // ---- prologue: stage tile 0 into buffer 0
  {
    GLOAD16(ksrc + (size_t)krow * 3072, (char*)Kl[0] + kdst);
    GLOAD16(ksrc + (size_t)(krow + 8) * 3072, (char*)Kl[0] + kdst + 1024);
    if (wid == 0) GLOAD4(mask + b * SEQ + lane, (char*)ml[0] + lane * 4);
    const us8 v0 = *(const us8*)(vsrc + (size_t)skr * 3072);
    const us8 v1 = *(const us8*)(vsrc + (size_t)(skr + 32) * 3072);
    char* vb = (char*)Vt[0];
#pragma unroll
    for (int i = 0; i < 8; ++i) {
      const int d = skc * 8 + i;
      *(u16*)(vb + d * 128 + ((2 * skr) ^ (i << 4))) = v0[i];
      *(u16*)(vb + d * 128 + ((2 * (skr + 32)) ^ (i << 4))) = v1[i];
    }
  }
  __syncthreads();

  for (int it = 0; it < NT; ++it) {
    const int cur = it & 1, nxt = cur ^ 1;
    const int ktn = (it + 1) * KB;
    const bool pre = (it + 1 < NT);
    us8 v0 = {}, v1 = {};
    if (pre) {  // issue next-tile loads; they fly during compute
      GLOAD16(ksrc + (size_t)(ktn + krow) * 3072, (char*)Kl[nxt] + kdst);
      GLOAD16(ksrc + (size_t)(ktn + krow + 8) * 3072, (char*)Kl[nxt] + kdst + 1024);
      if (wid == 0) GLOAD4(mask + b * SEQ + ktn + lane, (char*)ml[nxt] + lane * 4);
      v0 = *(const us8*)(vsrc + (size_t)(ktn + skr) * 3072);
      v1 = *(const us8*)(vsrc + (size_t)(ktn + skr + 32) * 3072);
    }

    // ---- S^T = mfma(K, Q): lane holds S[k=t16*16+g*4+j][q=fr]
    f32x4 s[4];
#pragma unroll
    for (int t16 = 0; t16 < 4; ++t16) {
      const int kr = t16 * 16 + fr;
      const char* krp = (const char*)Kl[cur] + kr * 128;
      const int sw = (kr & 7) << 4;
      const bf16x8 kf0 = *(const bf16x8*)(krp + ((g * 16) ^ sw));
      const bf16x8 kf1 = *(const bf16x8*)(krp + ((g * 16 + 64) ^ sw));
      f32x4 a = {0.f, 0.f, 0.f, 0.f};
      a = __builtin_amdgcn_mfma_f32_16x16x32_bf16(kf0, qf0, a, 0, 0, 0);
      a = __builtin_amdgcn_mfma_f32_16x16x32_bf16(kf1, qf1, a, 0, 0, 0);
      s[t16] = a;
    }

    // ---- mask + scale
#pragma unroll
    for (int t16 = 0; t16 < 4; ++t16) {
      const int4 mv = *(const int4*)&ml[cur][t16 * 16 + g * 4];
      const int* mp = (const int*)&mv;
#pragma unroll
      for (int j = 0; j < 4; ++j)
        s[t16][j] = (mp[j] == 0) ? -3e38f : s[t16][j] * 0.125f;
    }

    // ---- online softmax (per-lane scalar stats for q=fr)
    float rmax = s[0][0];
#pragma unroll
    for (int t16 = 0; t16 < 4; ++t16)
#pragma unroll
      for (int j = 0; j < 4; ++j) rmax = fmaxf(rmax, s[t16][j]);
    rmax = fmaxf(rmax, __shfl_xor(rmax, 16));
    rmax = fmaxf(rmax, __shfl_xor(rmax, 32));

    const float mn = fmaxf(mreg, rmax);
    const float sc = __expf(mreg - mn);
    mreg = mn;
    lreg *= sc;

    float p[4][4];
    float rsum = 0.f;
#pragma unroll
    for (int t16 = 0; t16 < 4; ++t16)
#pragma unroll
      for (int j = 0; j < 4; ++j) {
        p[t16][j] = __expf(s[t16][j] - mn);
        rsum += p[t16][j];
      }
    rsum += __shfl_xor(rsum, 16);
    rsum += __shfl_xor(rsum, 32);
    lreg += rsum;

    // rescale O (its rows are q = g*4+j; fetch that row's sc)
#pragma unroll
    for (int j = 0; j < 4; ++j) {
      const float scj = __shfl(sc, (g << 4) + g * 4 + j);
#pragma unroll
      for (int dt = 0; dt < 4; ++dt) o[dt][j] *= scj;
    }

    // ---- pack P to bf16 pairs (per t16: 2 dwords)
    u32 plo[4], phi[4];
#pragma unroll
    for (int t16 = 0; t16 < 4; ++t16) {
      plo[t16] = (u32)f2bf(p[t16][0]) | ((u32)f2bf(p[t16][1]) << 16);
      phi[t16] = (u32)f2bf(p[t16][2]) | ((u32)f2bf(p[t16][3]) << 16);
    }

    // ---- PV: A-frag gathered via shfl, B-frag = Vt rows (swizzled b128)
#pragma unroll
    for (int kh = 0; kh < 2; ++kh) {
      u32 fd[4];
#pragma unroll
      for (int hf = 0; hf < 2; ++hf) {
        const int sl = fr + ((((g & 1) << 1) + hf) << 4);
        const u32 c0l = (u32)__shfl((int)plo[kh * 2], sl);
        const u32 c0h = (u32)__shfl((int)phi[kh * 2], sl);
        const u32 c1l = (u32)__shfl((int)plo[kh * 2 + 1], sl);
        const u32 c1h = (u32)__shfl((int)phi[kh * 2 + 1], sl);
        const bool s1 = ((g >> 1) & 1) != 0;
        fd[hf * 2] = s1 ? c1l : c0l;
        fd[hf * 2 + 1] = s1 ? c1h : c0h;
      }
      union { u32 d[4]; bf16x8 v; } uu;
      uu.d[0] = fd[0]; uu.d[1] = fd[1]; uu.d[2] = fd[2]; uu.d[3] = fd[3];
      const bf16x8 pf = uu.v;
#pragma unroll
      for (int dt = 0; dt < 4; ++dt) {
        const int d = dt * 16 + fr;
        const bf16x8 vf = *(const bf16x8*)((const char*)Vt[cur] + d * 128 +
                                           ((g * 16 + kh * 64) ^ ((d & 7) << 4)));
        o[dt] = __builtin_amdgcn_mfma_f32_16x16x32_bf16(pf, vf, o[dt], 0, 0, 0);
      }
    }

    // ---- write next V tile (loads have had the whole compute to land)
    if (pre) {
      char* vb = (char*)Vt[nxt];
#pragma unroll
      for (int i = 0; i < 8; ++i) {
        const int d = skc * 8 + i;
        *(u16*)(vb + d * 128 + ((2 * skr) ^ (i << 4))) = v0[i];
        *(u16*)(vb + d * 128 + ((2 * (skr + 32)) ^ (i << 4))) = v1[i];
      }
    }
    __syncthreads();  // drains vmcnt+lgkmcnt: next tile fully staged
  }

  // ---- epilogue: O rows q = g*4+j need l from lane fr = g*4+j
  const float inv = 1.f / lreg;
#pragma unroll
  for (int j = 0; j < 4; ++j) {
    const float invj = __shfl(inv, (g << 4) + g * 4 + j);
    const int qrow = q0 + wid * 16 + g * 4 + j;
    u16* orow = Ob + (size_t)(b * SEQ + qrow) * DM + h * 64;
#pragma unroll
    for (int dt = 0; dt < 4; ++dt)
      orow[dt * 16 + fr] = f2bf(o[dt][j] * invj);
  }
}

// ---------------------------------------------------------------------------
// Fused residual-add + LayerNorm. A: fp32 or bf16; B: fp32; out: fp32 or bf16.
// ---------------------------------------------------------------------------
template <bool ABF, bool OBF>
__global__ __launch_bounds__(256) void ln_add(const void* __restrict__ Ap,
                                              const float* __restrict__ Bx,
                                              const float* __restrict__ g,
                                              const float* __restrict__ be,
                                              void* __restrict__ outp) {
  __shared__ float red[2][4];
  __shared__ float mu_s, sig_s;
  const int row = blockIdx.x;
  const int tid = threadIdx.x;

  float4 a;
  if (ABF) {
    const u16* ap = (const u16*)Ap + (size_t)row * DM + tid * 4;
    const ushort4 u = *(const ushort4*)ap;
    a = make_float4(bf2f(u.x), bf2f(u.y), bf2f(u.z), bf2f(u.w));
  } else {
    a = *(const float4*)((const float*)Ap + (size_t)row * DM + tid * 4);
  }
  const float4 b = *(const float4*)(Bx + (size_t)row * DM + tid * 4);
  float4 s = make_float4(a.x + b.x, a.y + b.y, a.z + b.z, a.w + b.w);

  float sum = s.x + s.y + s.z + s.w;
  float sq = s.x * s.x + s.y * s.y + s.z * s.z + s.w * s.w;
#pragma unroll
  for (int off = 32; off >= 1; off >>= 1) {
    sum += __shfl_xor(sum, off);
    sq += __shfl_xor(sq, off);
  }
  const int wid = tid >> 6;
  if ((tid & 63) == 0) { red[0][wid] = sum; red[1][wid] = sq; }
  __syncthreads();
  if (tid == 0) {
    float ts = red[0][0] + red[0][1] + red[0][2] + red[0][3];
    float tq = red[1][0] + red[1][1] + red[1][2] + red[1][3];
    float mu = ts * (1.f / DM);
    float var = tq * (1.f / DM) - mu * mu;
    mu_s = mu;
    sig_s = sqrtf(fmaxf(var, 0.f)) + 1e-6f;
  }
  __syncthreads();
  const float mu = mu_s, inv = 1.f / sig_s;
  const float4 gv = *(const float4*)(g + tid * 4);
  const float4 bv = *(const float4*)(be + tid * 4);
  float4 o;
  o.x = (s.x - mu) * inv * gv.x + bv.x;
  o.y = (s.y - mu) * inv * gv.y + bv.y;
  o.z = (s.z - mu) * inv * gv.z + bv.z;
  o.w = (s.w - mu) * inv * gv.w + bv.w;
  if (OBF) {
    u16* op = (u16*)outp + (size_t)row * DM + tid * 4;
    ushort4 o4;
    o4.x = f2bf(o.x); o4.y = f2bf(o.y); o4.z = f2bf(o.z); o4.w = f2bf(o.w);
    *(ushort4*)op = o4;
  } else {
    *(float4*)((float*)outp + (size_t)row * DM + tid * 4) = o;
  }
}

// ---------------------------------------------------------------------------
extern "C" void kernel_launch(void* const* d_in, const int* in_sizes, int n_in,
                              void* d_out, int out_size, void* d_ws,
                              size_t ws_size, hipStream_t stream) {
  const float* x  = (const float*)d_in[0];
  const int* mask = (const int*)d_in[1];
  const float* Wq = (const float*)d_in[2];
  const float* Wk = (const float*)d_in[3];
  const float* Wv = (const float*)d_in[4];
  const float* Wo = (const float*)d_in[5];
  const float* w1 = (const float*)d_in[6];
  const float* b1 = (const float*)d_in[7];
  const float* w2 = (const float*)d_in[8];
  const float* b2 = (const float*)d_in[9];
  const float* g1 = (const float*)d_in[10];
  const float* be1 = (const float*)d_in[11];
  const float* g2 = (const float*)d_in[12];
  const float* be2 = (const float*)d_in[13];
  float* out = (float*)d_out;
  float* ws = (float*)d_ws;

  // workspace layout (float offsets) — no overlaps among live ranges:
  //  QKVb  [0        .. 6291456)   4096x3072 bf16
  //  xb    [6291456  .. 8388608)   4096x1024 bf16
  //  Wqkvb [8388608  .. 9961472)   3072x1024 bf16
  //  Wob   [9961472  .. 10485760)  1024x1024 bf16
  //  w1b   [10485760 .. 12582912)  4096x1024 bf16
  //  w2b   [12582912 .. 14680064)  1024x4096 bf16
  //  Obf   [14680064 .. 16777216)  4096x1024 bf16
  //  X1    [16777216 .. 20971520)  4096x1024 f32
  //  X2b   [20971520 .. 23068672)  4096x1024 bf16
  //  X3    [23068672 .. 27262976)  4096x1024 f32
  //  Hb    [0        .. 8388608)   4096x4096 bf16 (reuses QKVb+xb, dead then)
  u16*   QKVb  = (u16*)(ws + 0);
  u16*   xb    = (u16*)(ws + 6291456);
  u16*   Wqkvb = (u16*)(ws + 8388608);
  u16*   Wob   = (u16*)(ws + 9961472);
  u16*   w1b   = (u16*)(ws + 10485760);
  u16*   w2b   = (u16*)(ws + 12582912);
  u16*   Obf   = (u16*)(ws + 14680064);
  float* X1    = ws + 16777216;
  u16*   X2b   = (u16*)(ws + 20971520);
  float* X3    = ws + 23068672;
  u16*   Hb    = (u16*)(ws + 0);

  const dim3 blk(256);

  cvt_bf16<<<2048, blk, 0, stream>>>(x, xb, MROWS * DM);
  cvt_bf16<<<512,  blk, 0, stream>>>(Wq, Wqkvb, DM * DM);
  cvt_bf16<<<512,  blk, 0, stream>>>(Wk, Wqkvb + DM * DM, DM * DM);
  cvt_bf16<<<512,  blk, 0, stream>>>(Wv, Wqkvb + 2 * DM * DM, DM * DM);
  cvt_bf16<<<512,  blk, 0, stream>>>(Wo, Wob, DM * DM);
  cvt_bf16<<<2048, blk, 0, stream>>>(w1, w1b, DFF * DM);
  cvt_bf16<<<2048, blk, 0, stream>>>(w2, w2b, DM * DFF);

  // fused QKV projection: [4096,3072] = xb @ Wqkvb^T, bf16 out
  gemm_bf16<128, 128, false, false, true><<<dim3(3072 / 128, MROWS / 128), blk, 0, stream>>>(
      xb, Wqkvb, nullptr, nullptr, QKVb, MROWS, 3072, DM);

  // MFMA flash attention v2 -> Obf
  attn_mfma<<<dim3(SEQ / 64, BSZ * NH), blk, 0, stream>>>(QKVb, mask, Obf);

  // X1 = O @ Wo^T (fp32 out)
  gemm_bf16<64, 128, false, false, false><<<dim3(DM / 128, MROWS / 64), blk, 0, stream>>>(
      Obf, Wob, nullptr, X1, nullptr, MROWS, DM, DM);

  // X2 = LN(X1 + x) -> bf16
  ln_add<false, true><<<dim3(MROWS), blk, 0, stream>>>(X1, x, g1, be1, X2b);

  // H = relu(X2 @ w1^T + b1) -> bf16
  gemm_bf16<128, 128, true, true, true><<<dim3(DFF / 128, MROWS / 128), blk, 0, stream>>>(
      X2b, w1b, b1, nullptr, Hb, MROWS, DFF, DM);

  // X3 = H @ w2^T + b2 -> fp32
  gemm_bf16<64, 128, true, false, false><<<dim3(DM / 128, MROWS / 64), blk, 0, stream>>>(
      Hb, w2b, b2, X3, nullptr, MROWS, DM, DFF);

  // out = LN(X2 + X3)
  ln_add<true, false><<<dim3(MROWS), blk, 0, stream>>>(X2b, X3, g2, be2, out);
}

// Round 6
// 344.824 us; speedup vs baseline: 6.9763x; 1.0995x over previous
//
#include <hip/hip_runtime.h>
#include <math.h>

typedef __attribute__((ext_vector_type(8))) short bf16x8;
typedef __attribute__((ext_vector_type(4))) float f32x4;
typedef __attribute__((ext_vector_type(8))) unsigned short us8;
typedef unsigned short u16;
typedef unsigned int u32;

constexpr int BSZ = 2, SEQ = 2048, DM = 1024, DFF = 4096, NH = 16, DH = 64;
constexpr int MROWS = BSZ * SEQ;  // 4096

__device__ __forceinline__ float bf2f(u16 u) {
  union { unsigned int i; float f; } v; v.i = ((unsigned int)u) << 16; return v.f;
}
__device__ __forceinline__ u16 f2bf(float f) {
  union { float f; unsigned int i; } v; v.f = f;
  unsigned int r = v.i + 0x7fffu + ((v.i >> 16) & 1u);
  return (u16)(r >> 16);
}

#define GLOAD16(gp, lp) __builtin_amdgcn_global_load_lds( \
    (const __attribute__((address_space(1))) void*)(gp),  \
    (__attribute__((address_space(3))) void*)(lp), 16, 0, 0)
#define GLOAD4(gp, lp) __builtin_amdgcn_global_load_lds( \
    (const __attribute__((address_space(1))) void*)(gp),  \
    (__attribute__((address_space(3))) void*)(lp), 4, 0, 0)

// ---------------------------------------------------------------------------
// fp32 -> bf16 convert (RNE), 8 elements/thread
// ---------------------------------------------------------------------------
__global__ __launch_bounds__(256) void cvt_bf16(const float* __restrict__ in,
                                                u16* __restrict__ out, int n) {
  const int i = (blockIdx.x * 256 + threadIdx.x) * 8;
  if (i >= n) return;
  const float4 a = *(const float4*)(in + i);
  const float4 b = *(const float4*)(in + i + 4);
  uint4 o;
  o.x = f2bf(a.x) | ((unsigned)f2bf(a.y) << 16);
  o.y = f2bf(a.z) | ((unsigned)f2bf(a.w) << 16);
  o.z = f2bf(b.x) | ((unsigned)f2bf(b.y) << 16);
  o.w = f2bf(b.z) | ((unsigned)f2bf(b.w) << 16);
  *(uint4*)(out + i) = o;
}

// ---------------------------------------------------------------------------
// bf16 MFMA GEMM (m97 structure): C[M,N] = A[M,K] * B[N,K]^T (+bias)(+relu)
// ---------------------------------------------------------------------------
template <int BM, int BN, bool BIAS, bool RELU, bool OBF16>
__global__ __launch_bounds__(256) void gemm_bf16(
    const u16* __restrict__ A, const u16* __restrict__ B,
    const float* __restrict__ bias, float* __restrict__ Cf,
    u16* __restrict__ Cb, int M, int N, int K) {
  constexpr int MI = BM / 32, NI = BN / 32;
  __shared__ u16 As[BM * 32];
  __shared__ u16 Bs[BN * 32];
  const int tid = threadIdx.x;
  const int lane = tid & 63, wid = tid >> 6;
  const int row0 = blockIdx.y * BM, col0 = blockIdx.x * BN;
  const int wr = (wid >> 1) * (BM / 2), wc = (wid & 1) * (BN / 2);
  const int fr = lane & 15, hi = lane >> 4;

  f32x4 acc[MI][NI];
#pragma unroll
  for (int i = 0; i < MI; ++i)
#pragma unroll
    for (int j = 0; j < NI; ++j) acc[i][j] = {0.f, 0.f, 0.f, 0.f};

  const int sr = tid >> 2;       // staging row within 64-row chunk
  const int se = (tid & 3) * 8;  // staging k-element offset

  for (int k0 = 0; k0 < K; k0 += 32) {
#pragma unroll
    for (int c = 0; c < BM * 64; c += 4096) {
      const int r = (c >> 6) + sr;
      GLOAD16(A + (size_t)(row0 + r) * K + (k0 + se), ((char*)As) + c + tid * 16);
    }
#pragma unroll
    for (int c = 0; c < BN * 64; c += 4096) {
      const int r = (c >> 6) + sr;
      GLOAD16(B + (size_t)(col0 + r) * K + (k0 + se), ((char*)Bs) + c + tid * 16);
    }
    __syncthreads();

    bf16x8 af[MI], bv[NI];
#pragma unroll
    for (int mi = 0; mi < MI; ++mi)
      af[mi] = *(const bf16x8*)&As[(wr + mi * 16 + fr) * 32 + hi * 8];
#pragma unroll
    for (int ni = 0; ni < NI; ++ni)
      bv[ni] = *(const bf16x8*)&Bs[(wc + ni * 16 + fr) * 32 + hi * 8];
#pragma unroll
    for (int mi = 0; mi < MI; ++mi)
#pragma unroll
      for (int ni = 0; ni < NI; ++ni)
        acc[mi][ni] = __builtin_amdgcn_mfma_f32_16x16x32_bf16(
            af[mi], bv[ni], acc[mi][ni], 0, 0, 0);
    __syncthreads();
  }

  const int erow = row0 + wr + (hi << 2);
  const int ecol0 = col0 + wc;
#pragma unroll
  for (int ni = 0; ni < NI; ++ni) {
    const int col = ecol0 + ni * 16 + fr;
    const float bvv = BIAS ? bias[col] : 0.f;
#pragma unroll
    for (int mi = 0; mi < MI; ++mi) {
      const int rbase = erow + mi * 16;
#pragma unroll
      for (int j = 0; j < 4; ++j) {
        float v = acc[mi][ni][j] + bvv;
        if (RELU) v = fmaxf(v, 0.f);
        const size_t idx = (size_t)(rbase + j) * N + col;
        if (OBF16) Cb[idx] = f2bf(v); else Cf[idx] = v;
      }
    }
  }
}

// ---------------------------------------------------------------------------
// MFMA flash attention v3. 4 waves/block, wave owns 16 q-rows. QB=KB=64.
// - K double-buffered via global_load_lds, source pre-swizzled (chunk^=(k&7)).
// - V double-buffered, transposed Vt[d][k]: thread packs adjacent k-rows
//   (2a,2a+1) into dwords -> 8 ds_write_b32, swizzle X(d)=(((d>>3)^d)&7)<<4.
//   Write banks = bijection over lanes (2/bank, b32 min) -> conflict-free.
//   Read chunks: 8 lanes/chunk-column, 8 distinct rows -> conflict-free.
// - Swapped QK^T: S^T = mfma(K, Q); per-lane scalar softmax stats.
// - P stays in registers: bf16 pack + 16 dword shfls build PV A-fragment.
// - One barrier per iter; prefetch in flight across compute.
// ---------------------------------------------------------------------------
__global__ __launch_bounds__(256) void attn_mfma(
    const u16* __restrict__ QKV, const int* __restrict__ mask,
    u16* __restrict__ Ob) {
  constexpr int KB = 64, QB = 64, NT = SEQ / KB;
  __shared__ u16 Kl[2][KB * 64];   // [k][d] rows 128B, chunk^=(k&7) swizzle
  __shared__ u16 Vt[2][64 * KB];   // [d][k] rows 128B, byte 2k ^ X(d)
  __shared__ int ml[2][KB];

  const int tid = threadIdx.x;
  const int lane = tid & 63, wid = tid >> 6;
  const int q0 = blockIdx.x * QB;
  const int bh = blockIdx.y;
  const int b = bh >> 4, h = bh & 15;
  const size_t base = (size_t)b * SEQ * 3072;
  const int fr = lane & 15, g = lane >> 4;

  // Q fragment (B-operand): row q = q0+wid*16+fr, elems d = g*8..+8 (+32)
  const u16* qp = QKV + base + (size_t)(q0 + wid * 16 + fr) * 3072 + h * 64 + g * 8;
  const bf16x8 qf0 = *(const bf16x8*)qp;
  const bf16x8 qf1 = *(const bf16x8*)(qp + 32);

  // K staging (global_load_lds, pre-swizzled source)
  const int krow = wid * 16 + (lane >> 3);          // +n*8 per instruction
  const int kcol = 8 * ((lane & 7) ^ (lane >> 3));  // inverse-swizzled chunk
  const u16* ksrc = QKV + base + 1024 + h * 64 + kcol;
  const int kdst = wid * 2048 + lane * 16;          // byte offset in K buffer

  // V staging: thread handles adjacent k-rows (2*va, 2*va+1), d-chunk vq
  const int va = tid >> 3;       // 0..31
  const int vq = tid & 7;        // 0..7
  const u16* vsrc = QKV + base + 2048 + h * 64 + vq * 8;

  f32x4 o[4] = {{0.f,0.f,0.f,0.f},{0.f,0.f,0.f,0.f},{0.f,0.f,0.f,0.f},{0.f,0.f,0.f,0.f}};
  float mreg = -3e38f, lreg = 0.f;

  // ---- prologue: stage tile 0 into buffer 0
  {
    GLOAD16(ksrc + (size_t)krow * 3072, (char*)Kl[0] + kdst);
    GLOAD16(ksrc + (size_t)(krow + 8) * 3072, (char*)Kl[0] + kdst + 1024);
    if (wid == 0) GLOAD4(mask + b * SEQ + lane, (char*)ml[0] + lane * 4);
    const us8 v0 = *(const us8*)(vsrc + (size_t)(2 * va) * 3072);
    const us8 v1 = *(const us8*)(vsrc + (size_t)(2 * va + 1) * 3072);
    char* vb = (char*)Vt[0];
#pragma unroll
    for (int i = 0; i < 8; ++i) {
      const int d = vq * 8 + i;
      const u32 wv = (u32)(u16)v0[i] | ((u32)(u16)v1[i] << 16);
      *(u32*)(vb + d * 128 + ((4 * va) ^ ((vq ^ i) << 4))) = wv;
    }
  }
  __syncthreads();

  for (int it = 0; it < NT; ++it) {
    const int cur = it & 1, nxt = cur ^ 1;
    const int ktn = (it + 1) * KB;
    const bool pre = (it + 1 < NT);
    us8 v0 = {}, v1 = {};
    if (pre) {  // issue next-tile loads; they fly during compute
      GLOAD16(ksrc + (size_t)(ktn + krow) * 3072, (char*)Kl[nxt] + kdst);
      GLOAD16(ksrc + (size_t)(ktn + krow + 8) * 3072, (char*)Kl[nxt] + kdst + 1024);
      if (wid == 0) GLOAD4(mask + b * SEQ + ktn + lane, (char*)ml[nxt] + lane * 4);
      v0 = *(const us8*)(vsrc + (size_t)(ktn + 2 * va) * 3072);
      v1 = *(const us8*)(vsrc + (size_t)(ktn + 2 * va + 1) * 3072);
    }

    // ---- S^T = mfma(K, Q): lane holds S[k=t16*16+g*4+j][q=fr]
    f32x4 s[4];
#pragma unroll
    for (int t16 = 0; t16 < 4; ++t16) {
      const int kr = t16 * 16 + fr;
      const char* krp = (const char*)Kl[cur] + kr * 128;
      const int sw = (kr & 7) << 4;
      const bf16x8 kf0 = *(const bf16x8*)(krp + ((g * 16) ^ sw));
      const bf16x8 kf1 = *(const bf16x8*)(krp + ((g * 16 + 64) ^ sw));
      f32x4 a = {0.f, 0.f, 0.f, 0.f};
      a = __builtin_amdgcn_mfma_f32_16x16x32_bf16(kf0, qf0, a, 0, 0, 0);
      a = __builtin_amdgcn_mfma_f32_16x16x32_bf16(kf1, qf1, a, 0, 0, 0);
      s[t16] = a;
    }

    // ---- mask + scale
#pragma unroll
    for (int t16 = 0; t16 < 4; ++t16) {
      const int4 mv = *(const int4*)&ml[cur][t16 * 16 + g * 4];
      const int* mp = (const int*)&mv;
#pragma unroll
      for (int j = 0; j < 4; ++j)
        s[t16][j] = (mp[j] == 0) ? -3e38f : s[t16][j] * 0.125f;
    }

    // ---- online softmax (per-lane scalar stats for q=fr)
    float rmax = s[0][0];
#pragma unroll
    for (int t16 = 0; t16 < 4; ++t16)
#pragma unroll
      for (int j = 0; j < 4; ++j) rmax = fmaxf(rmax, s[t16][j]);
    rmax = fmaxf(rmax, __shfl_xor(rmax, 16));
    rmax = fmaxf(rmax, __shfl_xor(rmax, 32));

    const float mn = fmaxf(mreg, rmax);
    const float sc = __expf(mreg - mn);
    mreg = mn;
    lreg *= sc;

    float p[4][4];
    float rsum = 0.f;
#pragma unroll
    for (int t16 = 0; t16 < 4; ++t16)
#pragma unroll
      for (int j = 0; j < 4; ++j) {
        p[t16][j] = __expf(s[t16][j] - mn);
        rsum += p[t16][j];
      }
    rsum += __shfl_xor(rsum, 16);
    rsum += __shfl_xor(rsum, 32);
    lreg += rsum;

    // rescale O (its rows are q = g*4+j; fetch that row's sc)
#pragma unroll
    for (int j = 0; j < 4; ++j) {
      const float scj = __shfl(sc, (g << 4) + g * 4 + j);
#pragma unroll
      for (int dt = 0; dt < 4; ++dt) o[dt][j] *= scj;
    }

    // ---- pack P to bf16 pairs (per t16: 2 dwords)
    u32 plo[4], phi[4];
#pragma unroll
    for (int t16 = 0; t16 < 4; ++t16) {
      plo[t16] = (u32)f2bf(p[t16][0]) | ((u32)f2bf(p[t16][1]) << 16);
      phi[t16] = (u32)f2bf(p[t16][2]) | ((u32)f2bf(p[t16][3]) << 16);
    }

    // ---- PV: A-frag gathered via shfl, B-frag = Vt rows (swizzled b128)
#pragma unroll
    for (int kh = 0; kh < 2; ++kh) {
      u32 fd[4];
#pragma unroll
      for (int hf = 0; hf < 2; ++hf) {
        const int sl = fr + ((((g & 1) << 1) + hf) << 4);
        const u32 c0l = (u32)__shfl((int)plo[kh * 2], sl);
        const u32 c0h = (u32)__shfl((int)phi[kh * 2], sl);
        const u32 c1l = (u32)__shfl((int)plo[kh * 2 + 1], sl);
        const u32 c1h = (u32)__shfl((int)phi[kh * 2 + 1], sl);
        const bool s1 = ((g >> 1) & 1) != 0;
        fd[hf * 2] = s1 ? c1l : c0l;
        fd[hf * 2 + 1] = s1 ? c1h : c0h;
      }
      union { u32 d[4]; bf16x8 v; } uu;
      uu.d[0] = fd[0]; uu.d[1] = fd[1]; uu.d[2] = fd[2]; uu.d[3] = fd[3];
      const bf16x8 pf = uu.v;
#pragma unroll
      for (int dt = 0; dt < 4; ++dt) {
        const int d = dt * 16 + fr;
        const int xd = (((d >> 3) ^ d) & 7) << 4;
        const bf16x8 vf = *(const bf16x8*)((const char*)Vt[cur] + d * 128 +
                                           ((g * 16 + kh * 64) ^ xd));
        o[dt] = __builtin_amdgcn_mfma_f32_16x16x32_bf16(pf, vf, o[dt], 0, 0, 0);
      }
    }

    // ---- write next V tile (loads have had the whole compute to land)
    if (pre) {
      char* vb = (char*)Vt[nxt];
#pragma unroll
      for (int i = 0; i < 8; ++i) {
        const int d = vq * 8 + i;
        const u32 wv = (u32)(u16)v0[i] | ((u32)(u16)v1[i] << 16);
        *(u32*)(vb + d * 128 + ((4 * va) ^ ((vq ^ i) << 4))) = wv;
      }
    }
    __syncthreads();  // drains vmcnt+lgkmcnt: next tile fully staged
  }

  // ---- epilogue: O rows q = g*4+j need l from lane fr = g*4+j
  const float inv = 1.f / lreg;
#pragma unroll
  for (int j = 0; j < 4; ++j) {
    const float invj = __shfl(inv, (g << 4) + g * 4 + j);
    const int qrow = q0 + wid * 16 + g * 4 + j;
    u16* orow = Ob + (size_t)(b * SEQ + qrow) * DM + h * 64;
#pragma unroll
    for (int dt = 0; dt < 4; ++dt)
      orow[dt * 16 + fr] = f2bf(o[dt][j] * invj);
  }
}

// ---------------------------------------------------------------------------
// Fused residual-add + LayerNorm. A: fp32 or bf16; B: fp32; out: fp32 or bf16.
// ---------------------------------------------------------------------------
template <bool ABF, bool OBF>
__global__ __launch_bounds__(256) void ln_add(const void* __restrict__ Ap,
                                              const float* __restrict__ Bx,
                                              const float* __restrict__ g,
                                              const float* __restrict__ be,
                                              void* __restrict__ outp) {
  __shared__ float red[2][4];
  __shared__ float mu_s, sig_s;
  const int row = blockIdx.x;
  const int tid = threadIdx.x;

  float4 a;
  if (ABF) {
    const u16* ap = (const u16*)Ap + (size_t)row * DM + tid * 4;
    const ushort4 u = *(const ushort4*)ap;
    a = make_float4(bf2f(u.x), bf2f(u.y), bf2f(u.z), bf2f(u.w));
  } else {
    a = *(const float4*)((const float*)Ap + (size_t)row * DM + tid * 4);
  }
  const float4 b = *(const float4*)(Bx + (size_t)row * DM + tid * 4);
  float4 s = make_float4(a.x + b.x, a.y + b.y, a.z + b.z, a.w + b.w);

  float sum = s.x + s.y + s.z + s.w;
  float sq = s.x * s.x + s.y * s.y + s.z * s.z + s.w * s.w;
#pragma unroll
  for (int off = 32; off >= 1; off >>= 1) {
    sum += __shfl_xor(sum, off);
    sq += __shfl_xor(sq, off);
  }
  const int wid = tid >> 6;
  if ((tid & 63) == 0) { red[0][wid] = sum; red[1][wid] = sq; }
  __syncthreads();
  if (tid == 0) {
    float ts = red[0][0] + red[0][1] + red[0][2] + red[0][3];
    float tq = red[1][0] + red[1][1] + red[1][2] + red[1][3];
    float mu = ts * (1.f / DM);
    float var = tq * (1.f / DM) - mu * mu;
    mu_s = mu;
    sig_s = sqrtf(fmaxf(var, 0.f)) + 1e-6f;
  }
  __syncthreads();
  const float mu = mu_s, inv = 1.f / sig_s;
  const float4 gv = *(const float4*)(g + tid * 4);
  const float4 bv = *(const float4*)(be + tid * 4);
  float4 o;
  o.x = (s.x - mu) * inv * gv.x + bv.x;
  o.y = (s.y - mu) * inv * gv.y + bv.y;
  o.z = (s.z - mu) * inv * gv.z + bv.z;
  o.w = (s.w - mu) * inv * gv.w + bv.w;
  if (OBF) {
    u16* op = (u16*)outp + (size_t)row * DM + tid * 4;
    ushort4 o4;
    o4.x = f2bf(o.x); o4.y = f2bf(o.y); o4.z = f2bf(o.z); o4.w = f2bf(o.w);
    *(ushort4*)op = o4;
  } else {
    *(float4*)((float*)outp + (size_t)row * DM + tid * 4) = o;
  }
}

// ---------------------------------------------------------------------------
extern "C" void kernel_launch(void* const* d_in, const int* in_sizes, int n_in,
                              void* d_out, int out_size, void* d_ws,
                              size_t ws_size, hipStream_t stream) {
  const float* x  = (const float*)d_in[0];
  const int* mask = (const int*)d_in[1];
  const float* Wq = (const float*)d_in[2];
  const float* Wk = (const float*)d_in[3];
  const float* Wv = (const float*)d_in[4];
  const float* Wo = (const float*)d_in[5];
  const float* w1 = (const float*)d_in[6];
  const float* b1 = (const float*)d_in[7];
  const float* w2 = (const float*)d_in[8];
  const float* b2 = (const float*)d_in[9];
  const float* g1 = (const float*)d_in[10];
  const float* be1 = (const float*)d_in[11];
  const float* g2 = (const float*)d_in[12];
  const float* be2 = (const float*)d_in[13];
  float* out = (float*)d_out;
  float* ws = (float*)d_ws;

  // workspace layout (float offsets) — no overlaps among live ranges:
  //  QKVb  [0        .. 6291456)   4096x3072 bf16
  //  xb    [6291456  .. 8388608)   4096x1024 bf16
  //  Wqkvb [8388608  .. 9961472)   3072x1024 bf16
  //  Wob   [9961472  .. 10485760)  1024x1024 bf16
  //  w1b   [10485760 .. 12582912)  4096x1024 bf16
  //  w2b   [12582912 .. 14680064)  1024x4096 bf16
  //  Obf   [14680064 .. 16777216)  4096x1024 bf16
  //  X1    [16777216 .. 20971520)  4096x1024 f32
  //  X2b   [20971520 .. 23068672)  4096x1024 bf16
  //  X3    [23068672 .. 27262976)  4096x1024 f32
  //  Hb    [0        .. 8388608)   4096x4096 bf16 (reuses QKVb+xb, dead then)
  u16*   QKVb  = (u16*)(ws + 0);
  u16*   xb    = (u16*)(ws + 6291456);
  u16*   Wqkvb = (u16*)(ws + 8388608);
  u16*   Wob   = (u16*)(ws + 9961472);
  u16*   w1b   = (u16*)(ws + 10485760);
  u16*   w2b   = (u16*)(ws + 12582912);
  u16*   Obf   = (u16*)(ws + 14680064);
  float* X1    = ws + 16777216;
  u16*   X2b   = (u16*)(ws + 20971520);
  float* X3    = ws + 23068672;
  u16*   Hb    = (u16*)(ws + 0);

  const dim3 blk(256);

  cvt_bf16<<<2048, blk, 0, stream>>>(x, xb, MROWS * DM);
  cvt_bf16<<<512,  blk, 0, stream>>>(Wq, Wqkvb, DM * DM);
  cvt_bf16<<<512,  blk, 0, stream>>>(Wk, Wqkvb + DM * DM, DM * DM);
  cvt_bf16<<<512,  blk, 0, stream>>>(Wv, Wqkvb + 2 * DM * DM, DM * DM);
  cvt_bf16<<<512,  blk, 0, stream>>>(Wo, Wob, DM * DM);
  cvt_bf16<<<2048, blk, 0, stream>>>(w1, w1b, DFF * DM);
  cvt_bf16<<<2048, blk, 0, stream>>>(w2, w2b, DM * DFF);

  // fused QKV projection: [4096,3072] = xb @ Wqkvb^T, bf16 out
  gemm_bf16<128, 128, false, false, true><<<dim3(3072 / 128, MROWS / 128), blk, 0, stream>>>(
      xb, Wqkvb, nullptr, nullptr, QKVb, MROWS, 3072, DM);

  // MFMA flash attention v3 -> Obf
  attn_mfma<<<dim3(SEQ / 64, BSZ * NH), blk, 0, stream>>>(QKVb, mask, Obf);

  // X1 = O @ Wo^T (fp32 out)
  gemm_bf16<64, 128, false, false, false><<<dim3(DM / 128, MROWS / 64), blk, 0, stream>>>(
      Obf, Wob, nullptr, X1, nullptr, MROWS, DM, DM);

  // X2 = LN(X1 + x) -> bf16
  ln_add<false, true><<<dim3(MROWS), blk, 0, stream>>>(X1, x, g1, be1, X2b);

  // H = relu(X2 @ w1^T + b1) -> bf16
  gemm_bf16<128, 128, true, true, true><<<dim3(DFF / 128, MROWS / 128), blk, 0, stream>>>(
      X2b, w1b, b1, nullptr, Hb, MROWS, DFF, DM);

  // X3 = H @ w2^T + b2 -> fp32
  gemm_bf16<64, 128, true, false, false><<<dim3(DM / 128, MROWS / 64), blk, 0, stream>>>(
      Hb, w2b, b2, X3, nullptr, MROWS, DM, DFF);

  // out = LN(X2 + X3)
  ln_add<true, false><<<dim3(MROWS), blk, 0, stream>>>(X2b, X3, g2, be2, out);
}

// Round 7
// 318.989 us; speedup vs baseline: 7.5413x; 1.0810x over previous
//
#include <hip/hip_runtime.h>
#include <math.h>

typedef __attribute__((ext_vector_type(8))) short bf16x8;
typedef __attribute__((ext_vector_type(4))) float f32x4;
typedef __attribute__((ext_vector_type(8))) unsigned short us8;
typedef unsigned short u16;
typedef unsigned int u32;

constexpr int BSZ = 2, SEQ = 2048, DM = 1024, DFF = 4096, NH = 16, DH = 64;
constexpr int MROWS = BSZ * SEQ;  // 4096

__device__ __forceinline__ float bf2f(u16 u) {
  union { unsigned int i; float f; } v; v.i = ((unsigned int)u) << 16; return v.f;
}
__device__ __forceinline__ u16 f2bf(float f) {
  union { float f; unsigned int i; } v; v.f = f;
  unsigned int r = v.i + 0x7fffu + ((v.i >> 16) & 1u);
  return (u16)(r >> 16);
}

#define GLOAD16(gp, lp) __builtin_amdgcn_global_load_lds( \
    (const __attribute__((address_space(1))) void*)(gp),  \
    (__attribute__((address_space(3))) void*)(lp), 16, 0, 0)
#define GLOAD4(gp, lp) __builtin_amdgcn_global_load_lds( \
    (const __attribute__((address_space(1))) void*)(gp),  \
    (__attribute__((address_space(3))) void*)(lp), 4, 0, 0)

// ---------------------------------------------------------------------------
// fp32 -> bf16 convert (RNE), 8 elements/thread
// ---------------------------------------------------------------------------
__global__ __launch_bounds__(256) void cvt_bf16(const float* __restrict__ in,
                                                u16* __restrict__ out, int n) {
  const int i = (blockIdx.x * 256 + threadIdx.x) * 8;
  if (i >= n) return;
  const float4 a = *(const float4*)(in + i);
  const float4 b = *(const float4*)(in + i + 4);
  uint4 o;
  o.x = f2bf(a.x) | ((unsigned)f2bf(a.y) << 16);
  o.y = f2bf(a.z) | ((unsigned)f2bf(a.w) << 16);
  o.z = f2bf(b.x) | ((unsigned)f2bf(b.y) << 16);
  o.w = f2bf(b.z) | ((unsigned)f2bf(b.w) << 16);
  *(uint4*)(out + i) = o;
}

// ---------------------------------------------------------------------------
// bf16 MFMA GEMM, 2-phase double-buffered (T3 minimum) + XCD swizzle (T1).
// C[M,N] = A[M,K] * B[N,K]^T (+bias)(+relu). BK=32, 256 thr = 4 waves (2x2).
// ---------------------------------------------------------------------------
template <int BM, int BN, bool BIAS, bool RELU, bool OBF16>
__global__ __launch_bounds__(256) void gemm_bf16(
    const u16* __restrict__ A, const u16* __restrict__ B,
    const float* __restrict__ bias, float* __restrict__ Cf,
    u16* __restrict__ Cb, int M, int N, int K) {
  constexpr int MI = BM / 32, NI = BN / 32;
  __shared__ u16 As[2][BM * 32];
  __shared__ u16 Bs[2][BN * 32];
  const int tid = threadIdx.x;
  const int lane = tid & 63, wid = tid >> 6;

  // XCD-aware bijective swizzle (all grids have nwg % 8 == 0)
  const int nwg = gridDim.x * gridDim.y;
  int id = blockIdx.y * gridDim.x + blockIdx.x;
  id = (id & 7) * (nwg >> 3) + (id >> 3);
  const int bx = id % gridDim.x, by = id / gridDim.x;

  const int row0 = by * BM, col0 = bx * BN;
  const int wr = (wid >> 1) * (BM / 2), wc = (wid & 1) * (BN / 2);
  const int fr = lane & 15, hi = lane >> 4;

  f32x4 acc[MI][NI];
#pragma unroll
  for (int i = 0; i < MI; ++i)
#pragma unroll
    for (int j = 0; j < NI; ++j) acc[i][j] = {0.f, 0.f, 0.f, 0.f};

  const int sr = tid >> 2;       // staging row within 64-row chunk
  const int se = (tid & 3) * 8;  // staging k-element offset

#define STAGE(buf, k0)                                                        \
  {                                                                           \
    _Pragma("unroll")                                                         \
    for (int c = 0; c < BM * 64; c += 4096) {                                 \
      const int r = (c >> 6) + sr;                                            \
      GLOAD16(A + (size_t)(row0 + r) * K + ((k0) + se),                       \
              ((char*)As[buf]) + c + tid * 16);                               \
    }                                                                         \
    _Pragma("unroll")                                                         \
    for (int c = 0; c < BN * 64; c += 4096) {                                 \
      const int r = (c >> 6) + sr;                                            \
      GLOAD16(B + (size_t)(col0 + r) * K + ((k0) + se),                       \
              ((char*)Bs[buf]) + c + tid * 16);                               \
    }                                                                         \
  }

  STAGE(0, 0);
  __syncthreads();  // drains vmcnt -> buf0 ready

  const int NIT = K / 32;
  for (int it = 0; it < NIT; ++it) {
    const int cur = it & 1;
    if (it + 1 < NIT) STAGE(cur ^ 1, (it + 1) * 32);  // fly during compute

    bf16x8 af[MI], bv[NI];
#pragma unroll
    for (int mi = 0; mi < MI; ++mi)
      af[mi] = *(const bf16x8*)&As[cur][(wr + mi * 16 + fr) * 32 + hi * 8];
#pragma unroll
    for (int ni = 0; ni < NI; ++ni)
      bv[ni] = *(const bf16x8*)&Bs[cur][(wc + ni * 16 + fr) * 32 + hi * 8];
#pragma unroll
    for (int mi = 0; mi < MI; ++mi)
#pragma unroll
      for (int ni = 0; ni < NI; ++ni)
        acc[mi][ni] = __builtin_amdgcn_mfma_f32_16x16x32_bf16(
            af[mi], bv[ni], acc[mi][ni], 0, 0, 0);
    __syncthreads();  // drains vmcnt+lgkmcnt: next buf staged, reads done
  }
#undef STAGE

  const int erow = row0 + wr + (hi << 2);
  const int ecol0 = col0 + wc;
#pragma unroll
  for (int ni = 0; ni < NI; ++ni) {
    const int col = ecol0 + ni * 16 + fr;
    const float bvv = BIAS ? bias[col] : 0.f;
#pragma unroll
    for (int mi = 0; mi < MI; ++mi) {
      const int rbase = erow + mi * 16;
#pragma unroll
      for (int j = 0; j < 4; ++j) {
        float v = acc[mi][ni][j] + bvv;
        if (RELU) v = fmaxf(v, 0.f);
        const size_t idx = (size_t)(rbase + j) * N + col;
        if (OBF16) Cb[idx] = f2bf(v); else Cf[idx] = v;
      }
    }
  }
}

// ---------------------------------------------------------------------------
// MFMA flash attention v4. v3 + cvt_pk P-pack (T12 mech) + defer-max (T13).
// ---------------------------------------------------------------------------
__global__ __launch_bounds__(256) void attn_mfma(
    const u16* __restrict__ QKV, const int* __restrict__ mask,
    u16* __restrict__ Ob) {
  constexpr int KB = 64, QB = 64, NT = SEQ / KB;
  __shared__ u16 Kl[2][KB * 64];   // [k][d] rows 128B, chunk^=(k&7) swizzle
  __shared__ u16 Vt[2][64 * KB];   // [d][k] rows 128B, byte 2k ^ X(d)
  __shared__ int ml[2][KB];

  const int tid = threadIdx.x;
  const int lane = tid & 63, wid = tid >> 6;
  const int q0 = blockIdx.x * QB;
  const int bh = blockIdx.y;
  const int b = bh >> 4, h = bh & 15;
  const size_t base = (size_t)b * SEQ * 3072;
  const int fr = lane & 15, g = lane >> 4;

  // Q fragment (B-operand): row q = q0+wid*16+fr, elems d = g*8..+8 (+32)
  const u16* qp = QKV + base + (size_t)(q0 + wid * 16 + fr) * 3072 + h * 64 + g * 8;
  const bf16x8 qf0 = *(const bf16x8*)qp;
  const bf16x8 qf1 = *(const bf16x8*)(qp + 32);

  // K staging (global_load_lds, pre-swizzled source)
  const int krow = wid * 16 + (lane >> 3);          // +n*8 per instruction
  const int kcol = 8 * ((lane & 7) ^ (lane >> 3));  // inverse-swizzled chunk
  const u16* ksrc = QKV + base + 1024 + h * 64 + kcol;
  const int kdst = wid * 2048 + lane * 16;          // byte offset in K buffer

  // V staging: thread handles adjacent k-rows (2*va, 2*va+1), d-chunk vq
  const int va = tid >> 3;       // 0..31
  const int vq = tid & 7;        // 0..7
  const u16* vsrc = QKV + base + 2048 + h * 64 + vq * 8;

  f32x4 o[4] = {{0.f,0.f,0.f,0.f},{0.f,0.f,0.f,0.f},{0.f,0.f,0.f,0.f},{0.f,0.f,0.f,0.f}};
  float mreg = -3e38f, lreg = 0.f;

  // ---- prologue: stage tile 0 into buffer 0
  {
    GLOAD16(ksrc + (size_t)krow * 3072, (char*)Kl[0] + kdst);
    GLOAD16(ksrc + (size_t)(krow + 8) * 3072, (char*)Kl[0] + kdst + 1024);
    if (wid == 0) GLOAD4(mask + b * SEQ + lane, (char*)ml[0] + lane * 4);
    const us8 v0 = *(const us8*)(vsrc + (size_t)(2 * va) * 3072);
    const us8 v1 = *(const us8*)(vsrc + (size_t)(2 * va + 1) * 3072);
    char* vb = (char*)Vt[0];
#pragma unroll
    for (int i = 0; i < 8; ++i) {
      const int d = vq * 8 + i;
      const u32 wv = (u32)(u16)v0[i] | ((u32)(u16)v1[i] << 16);
      *(u32*)(vb + d * 128 + ((4 * va) ^ ((vq ^ i) << 4))) = wv;
    }
  }
  __syncthreads();

  for (int it = 0; it < NT; ++it) {
    const int cur = it & 1, nxt = cur ^ 1;
    const int ktn = (it + 1) * KB;
    const bool pre = (it + 1 < NT);
    us8 v0 = {}, v1 = {};
    if (pre) {  // issue next-tile loads; they fly during compute
      GLOAD16(ksrc + (size_t)(ktn + krow) * 3072, (char*)Kl[nxt] + kdst);
      GLOAD16(ksrc + (size_t)(ktn + krow + 8) * 3072, (char*)Kl[nxt] + kdst + 1024);
      if (wid == 0) GLOAD4(mask + b * SEQ + ktn + lane, (char*)ml[nxt] + lane * 4);
      v0 = *(const us8*)(vsrc + (size_t)(ktn + 2 * va) * 3072);
      v1 = *(const us8*)(vsrc + (size_t)(ktn + 2 * va + 1) * 3072);
    }

    // ---- S^T = mfma(K, Q): lane holds S[k=t16*16+g*4+j][q=fr]
    f32x4 s[4];
#pragma unroll
    for (int t16 = 0; t16 < 4; ++t16) {
      const int kr = t16 * 16 + fr;
      const char* krp = (const char*)Kl[cur] + kr * 128;
      const int sw = (kr & 7) << 4;
      const bf16x8 kf0 = *(const bf16x8*)(krp + ((g * 16) ^ sw));
      const bf16x8 kf1 = *(const bf16x8*)(krp + ((g * 16 + 64) ^ sw));
      f32x4 a = {0.f, 0.f, 0.f, 0.f};
      a = __builtin_amdgcn_mfma_f32_16x16x32_bf16(kf0, qf0, a, 0, 0, 0);
      a = __builtin_amdgcn_mfma_f32_16x16x32_bf16(kf1, qf1, a, 0, 0, 0);
      s[t16] = a;
    }

    // ---- mask + scale
#pragma unroll
    for (int t16 = 0; t16 < 4; ++t16) {
      const int4 mv = *(const int4*)&ml[cur][t16 * 16 + g * 4];
      const int* mp = (const int*)&mv;
#pragma unroll
      for (int j = 0; j < 4; ++j)
        s[t16][j] = (mp[j] == 0) ? -3e38f : s[t16][j] * 0.125f;
    }

    // ---- online softmax with defer-max (T13, THR=8)
    float rmax = s[0][0];
#pragma unroll
    for (int t16 = 0; t16 < 4; ++t16)
#pragma unroll
      for (int j = 0; j < 4; ++j) rmax = fmaxf(rmax, s[t16][j]);
    rmax = fmaxf(rmax, __shfl_xor(rmax, 16));
    rmax = fmaxf(rmax, __shfl_xor(rmax, 32));

    if (!__all(rmax <= mreg + 8.f)) {
      const float mn = fmaxf(mreg, rmax);
      const float sc = __expf(mreg - mn);
      mreg = mn;
      lreg *= sc;
#pragma unroll
      for (int j = 0; j < 4; ++j) {
        const float scj = __shfl(sc, (g << 4) + g * 4 + j);
#pragma unroll
        for (int dt = 0; dt < 4; ++dt) o[dt][j] *= scj;
      }
    }

    float p[4][4];
    float rsum = 0.f;
#pragma unroll
    for (int t16 = 0; t16 < 4; ++t16)
#pragma unroll
      for (int j = 0; j < 4; ++j) {
        p[t16][j] = __expf(s[t16][j] - mreg);  // bounded by e^8
        rsum += p[t16][j];
      }
    rsum += __shfl_xor(rsum, 16);
    rsum += __shfl_xor(rsum, 32);
    lreg += rsum;

    // ---- pack P to bf16 pairs via v_cvt_pk_bf16_f32 (lo=src0, hi=src1)
    u32 plo[4], phi[4];
#pragma unroll
    for (int t16 = 0; t16 < 4; ++t16) {
      asm("v_cvt_pk_bf16_f32 %0, %1, %2"
          : "=v"(plo[t16]) : "v"(p[t16][0]), "v"(p[t16][1]));
      asm("v_cvt_pk_bf16_f32 %0, %1, %2"
          : "=v"(phi[t16]) : "v"(p[t16][2]), "v"(p[t16][3]));
    }

    // ---- PV: A-frag gathered via shfl, B-frag = Vt rows (swizzled b128)
#pragma unroll
    for (int kh = 0; kh < 2; ++kh) {
      u32 fd[4];
#pragma unroll
      for (int hf = 0; hf < 2; ++hf) {
        const int sl = fr + ((((g & 1) << 1) + hf) << 4);
        const u32 c0l = (u32)__shfl((int)plo[kh * 2], sl);
        const u32 c0h = (u32)__shfl((int)phi[kh * 2], sl);
        const u32 c1l = (u32)__shfl((int)plo[kh * 2 + 1], sl);
        const u32 c1h = (u32)__shfl((int)phi[kh * 2 + 1], sl);
        const bool s1 = ((g >> 1) & 1) != 0;
        fd[hf * 2] = s1 ? c1l : c0l;
        fd[hf * 2 + 1] = s1 ? c1h : c0h;
      }
      union { u32 d[4]; bf16x8 v; } uu;
      uu.d[0] = fd[0]; uu.d[1] = fd[1]; uu.d[2] = fd[2]; uu.d[3] = fd[3];
      const bf16x8 pf = uu.v;
#pragma unroll
      for (int dt = 0; dt < 4; ++dt) {
        const int d = dt * 16 + fr;
        const int xd = (((d >> 3) ^ d) & 7) << 4;
        const bf16x8 vf = *(const bf16x8*)((const char*)Vt[cur] + d * 128 +
                                           ((g * 16 + kh * 64) ^ xd));
        o[dt] = __builtin_amdgcn_mfma_f32_16x16x32_bf16(pf, vf, o[dt], 0, 0, 0);
      }
    }

    // ---- write next V tile (loads have had the whole compute to land)
    if (pre) {
      char* vb = (char*)Vt[nxt];
#pragma unroll
      for (int i = 0; i < 8; ++i) {
        const int d = vq * 8 + i;
        const u32 wv = (u32)(u16)v0[i] | ((u32)(u16)v1[i] << 16);
        *(u32*)(vb + d * 128 + ((4 * va) ^ ((vq ^ i) << 4))) = wv;
      }
    }
    __syncthreads();  // drains vmcnt+lgkmcnt: next tile fully staged
  }

  // ---- epilogue: O rows q = g*4+j need l from lane fr = g*4+j
  const float inv = 1.f / lreg;
#pragma unroll
  for (int j = 0; j < 4; ++j) {
    const float invj = __shfl(inv, (g << 4) + g * 4 + j);
    const int qrow = q0 + wid * 16 + g * 4 + j;
    u16* orow = Ob + (size_t)(b * SEQ + qrow) * DM + h * 64;
#pragma unroll
    for (int dt = 0; dt < 4; ++dt)
      orow[dt * 16 + fr] = f2bf(o[dt][j] * invj);
  }
}

// ---------------------------------------------------------------------------
// Fused residual-add + LayerNorm. A: fp32 or bf16; B: fp32; out: fp32 or bf16.
// ---------------------------------------------------------------------------
template <bool ABF, bool OBF>
__global__ __launch_bounds__(256) void ln_add(const void* __restrict__ Ap,
                                              const float* __restrict__ Bx,
                                              const float* __restrict__ g,
                                              const float* __restrict__ be,
                                              void* __restrict__ outp) {
  __shared__ float red[2][4];
  __shared__ float mu_s, sig_s;
  const int row = blockIdx.x;
  const int tid = threadIdx.x;

  float4 a;
  if (ABF) {
    const u16* ap = (const u16*)Ap + (size_t)row * DM + tid * 4;
    const ushort4 u = *(const ushort4*)ap;
    a = make_float4(bf2f(u.x), bf2f(u.y), bf2f(u.z), bf2f(u.w));
  } else {
    a = *(const float4*)((const float*)Ap + (size_t)row * DM + tid * 4);
  }
  const float4 b = *(const float4*)(Bx + (size_t)row * DM + tid * 4);
  float4 s = make_float4(a.x + b.x, a.y + b.y, a.z + b.z, a.w + b.w);

  float sum = s.x + s.y + s.z + s.w;
  float sq = s.x * s.x + s.y * s.y + s.z * s.z + s.w * s.w;
#pragma unroll
  for (int off = 32; off >= 1; off >>= 1) {
    sum += __shfl_xor(sum, off);
    sq += __shfl_xor(sq, off);
  }
  const int wid = tid >> 6;
  if ((tid & 63) == 0) { red[0][wid] = sum; red[1][wid] = sq; }
  __syncthreads();
  if (tid == 0) {
    float ts = red[0][0] + red[0][1] + red[0][2] + red[0][3];
    float tq = red[1][0] + red[1][1] + red[1][2] + red[1][3];
    float mu = ts * (1.f / DM);
    float var = tq * (1.f / DM) - mu * mu;
    mu_s = mu;
    sig_s = sqrtf(fmaxf(var, 0.f)) + 1e-6f;
  }
  __syncthreads();
  const float mu = mu_s, inv = 1.f / sig_s;
  const float4 gv = *(const float4*)(g + tid * 4);
  const float4 bv = *(const float4*)(be + tid * 4);
  float4 o;
  o.x = (s.x - mu) * inv * gv.x + bv.x;
  o.y = (s.y - mu) * inv * gv.y + bv.y;
  o.z = (s.z - mu) * inv * gv.z + bv.z;
  o.w = (s.w - mu) * inv * gv.w + bv.w;
  if (OBF) {
    u16* op = (u16*)outp + (size_t)row * DM + tid * 4;
    ushort4 o4;
    o4.x = f2bf(o.x); o4.y = f2bf(o.y); o4.z = f2bf(o.z); o4.w = f2bf(o.w);
    *(ushort4*)op = o4;
  } else {
    *(float4*)((float*)outp + (size_t)row * DM + tid * 4) = o;
  }
}

// ---------------------------------------------------------------------------
extern "C" void kernel_launch(void* const* d_in, const int* in_sizes, int n_in,
                              void* d_out, int out_size, void* d_ws,
                              size_t ws_size, hipStream_t stream) {
  const float* x  = (const float*)d_in[0];
  const int* mask = (const int*)d_in[1];
  const float* Wq = (const float*)d_in[2];
  const float* Wk = (const float*)d_in[3];
  const float* Wv = (const float*)d_in[4];
  const float* Wo = (const float*)d_in[5];
  const float* w1 = (const float*)d_in[6];
  const float* b1 = (const float*)d_in[7];
  const float* w2 = (const float*)d_in[8];
  const float* b2 = (const float*)d_in[9];
  const float* g1 = (const float*)d_in[10];
  const float* be1 = (const float*)d_in[11];
  const float* g2 = (const float*)d_in[12];
  const float* be2 = (const float*)d_in[13];
  float* out = (float*)d_out;
  float* ws = (float*)d_ws;

  // workspace layout (float offsets) — no overlaps among live ranges:
  //  QKVb  [0        .. 6291456)   4096x3072 bf16
  //  xb    [6291456  .. 8388608)   4096x1024 bf16
  //  Wqkvb [8388608  .. 9961472)   3072x1024 bf16
  //  Wob   [9961472  .. 10485760)  1024x1024 bf16
  //  w1b   [10485760 .. 12582912)  4096x1024 bf16
  //  w2b   [12582912 .. 14680064)  1024x4096 bf16
  //  Obf   [14680064 .. 16777216)  4096x1024 bf16
  //  X1    [16777216 .. 20971520)  4096x1024 f32
  //  X2b   [20971520 .. 23068672)  4096x1024 bf16
  //  X3    [23068672 .. 27262976)  4096x1024 f32
  //  Hb    [0        .. 8388608)   4096x4096 bf16 (reuses QKVb+xb, dead then)
  u16*   QKVb  = (u16*)(ws + 0);
  u16*   xb    = (u16*)(ws + 6291456);
  u16*   Wqkvb = (u16*)(ws + 8388608);
  u16*   Wob   = (u16*)(ws + 9961472);
  u16*   w1b   = (u16*)(ws + 10485760);
  u16*   w2b   = (u16*)(ws + 12582912);
  u16*   Obf   = (u16*)(ws + 14680064);
  float* X1    = ws + 16777216;
  u16*   X2b   = (u16*)(ws + 20971520);
  float* X3    = ws + 23068672;
  u16*   Hb    = (u16*)(ws + 0);

  const dim3 blk(256);

  cvt_bf16<<<2048, blk, 0, stream>>>(x, xb, MROWS * DM);
  cvt_bf16<<<512,  blk, 0, stream>>>(Wq, Wqkvb, DM * DM);
  cvt_bf16<<<512,  blk, 0, stream>>>(Wk, Wqkvb + DM * DM, DM * DM);
  cvt_bf16<<<512,  blk, 0, stream>>>(Wv, Wqkvb + 2 * DM * DM, DM * DM);
  cvt_bf16<<<512,  blk, 0, stream>>>(Wo, Wob, DM * DM);
  cvt_bf16<<<2048, blk, 0, stream>>>(w1, w1b, DFF * DM);
  cvt_bf16<<<2048, blk, 0, stream>>>(w2, w2b, DM * DFF);

  // fused QKV projection: [4096,3072] = xb @ Wqkvb^T, bf16 out
  gemm_bf16<128, 128, false, false, true><<<dim3(3072 / 128, MROWS / 128), blk, 0, stream>>>(
      xb, Wqkvb, nullptr, nullptr, QKVb, MROWS, 3072, DM);

  // MFMA flash attention v4 -> Obf
  attn_mfma<<<dim3(SEQ / 64, BSZ * NH), blk, 0, stream>>>(QKVb, mask, Obf);

  // X1 = O @ Wo^T (fp32 out)
  gemm_bf16<64, 128, false, false, false><<<dim3(DM / 128, MROWS / 64), blk, 0, stream>>>(
      Obf, Wob, nullptr, X1, nullptr, MROWS, DM, DM);

  // X2 = LN(X1 + x) -> bf16
  ln_add<false, true><<<dim3(MROWS), blk, 0, stream>>>(X1, x, g1, be1, X2b);

  // H = relu(X2 @ w1^T + b1) -> bf16
  gemm_bf16<128, 128, true, true, true><<<dim3(DFF / 128, MROWS / 128), blk, 0, stream>>>(
      X2b, w1b, b1, nullptr, Hb, MROWS, DFF, DM);

  // X3 = H @ w2^T + b2 -> fp32
  gemm_bf16<64, 128, true, false, false><<<dim3(DM / 128, MROWS / 64), blk, 0, stream>>>(
      Hb, w2b, b2, X3, nullptr, MROWS, DM, DFF);

  // out = LN(X2 + X3)
  ln_add<true, false><<<dim3(MROWS), blk, 0, stream>>>(X2b, X3, g2, be2, out);
}